// Round 5
// baseline (927.977 us; speedup 1.0000x reference)
//
#include <hip/hip_runtime.h>
#include <math.h>

typedef unsigned int u32;
typedef unsigned long long u64;

#define B_ 16
#define L_ 1024
#define H_ 8
#define E_ 64
#define C_ 512            // H_*E_
#define NB_SEL 8          // blocks per (scale,b) in k_sel
#define GCH 8             // channels per k_stats block
#define TC 32             // k_corr time-chunk
#define CAPR 160          // k_corr<S> circular K-buffer rows (= 127 + TC + 1)
#define CAP1 192          // k_corr1 ring rows: 127 hist + 32 cur + 32 async-stage

// scale indexing: sidx 0 -> s=1 (Ls=1024), 1 -> s=2 (512), 2 -> s=4 (256)
__device__ __forceinline__ size_t co(int sidx) {       // corr elem offset
  return sidx == 0 ? 0u : (sidx == 1 ? 8388608u : 12582912u);
}
__device__ __forceinline__ u32 pk_off(int sidx) {      // pk elem offset in o-region
  return sidx == 0 ? 0u : (sidx == 1 ? 3211264u : 4816896u);
}
__device__ __forceinline__ u32 pk_cap(int sidx) { return 200704u >> sidx; }

__device__ __forceinline__ u32 f2key(float f) {
  u32 u = __float_as_uint(f);
  return (u & 0x80000000u) ? ~u : (u | 0x80000000u);
}
__device__ __forceinline__ float key2f(u32 k) {
  u32 u = (k & 0x80000000u) ? (k ^ 0x80000000u) : ~k;
  return __uint_as_float(u);
}

// direct global->LDS DMA, 16B/lane; LDS dest = wave-uniform base + lane*16
using u32g = __attribute__((address_space(1))) const unsigned int;
using u32l = __attribute__((address_space(3))) unsigned int;
__device__ __forceinline__ void gload16(const float* g, float* l) {
  __builtin_amdgcn_global_load_lds((u32g*)g, (u32l*)l, 16, 0, 0);
}

// ---------------------------------------------------------------------------
// K_init: zero control state once (single-pass pipeline -> no mid-run resets)
// ---------------------------------------------------------------------------
__global__ void k_init(u32* histA, u32* histB, u32* peak_cnt, u32* done,
                       double* s1, double* s2, float* cm) {
  const int gid = blockIdx.x * 256 + threadIdx.x;
  const int gs = gridDim.x * 256;
  for (int i = gid; i < 3 * 16 * 256; i += gs) { histA[i] = 0; histB[i] = 0; }
  for (int i = gid; i < 3 * 16 * 1024; i += gs) cm[i] = 0.f;
  for (int i = gid; i < 3 * 16 * 16; i += gs) peak_cnt[i] = 0;
  for (int i = gid; i < 144; i += gs) done[i] = 0;
  for (int i = gid; i < 48; i += gs) { s1[i] = 0.0; s2[i] = 0.0; }
}

// ---------------------------------------------------------------------------
// K1-S1: circular cross-correlation, fp32 direct, register-tiled.
// 512 threads / 8 waves, 16 taus per wave (r2 proven structure), with the q
// LDS path DELETED: q read scalar from global in the FMA loop (256B/wave
// coalesced; 8 waves/block share the same 8KB/chunk -> L2-served).
//  - LDS reads/wave-chunk: 79 -> 47 (km only) => LDS pipe ~280k cyc/CU
//    ~= FMA floor 262k cyc/SIMD: FMA-balanced instead of LDS-bound.
//  - LDS 48KB (K ring only) -> 3 blocks/CU = 24 waves/CU = 6 waves/SIMD.
//  - __launch_bounds__(512,6) caps VGPR at 85; live set ~66
//    (acc16 + km<=32 + q pipeline) -> no AGPR-move traffic (r0/r4 disease).
//  - K ring 192 rows via global_load_lds DMA, stage region disjoint -> ONE
//    barrier per chunk.
// ---------------------------------------------------------------------------
__launch_bounds__(512, 6)
__global__ void k_corr1(const float* __restrict__ Q, const float* __restrict__ K,
                        float* __restrict__ corr) {
  constexpr int LS = 1024;
  constexpr int LMASK = LS - 1;
  constexpr int NCHUNK = LS / TC;     // 32
  __shared__ float ks[CAP1 * 64];     // 48KB ring [p][e]; reused for transpose
  const int tid = threadIdx.x;        // 0..511
  const int e = tid & 63;
  const int slot16 = __builtin_amdgcn_readfirstlane((tid >> 6) << 4); // wave*16
  const int wb = __builtin_amdgcn_readfirstlane((tid >> 6) << 8);     // wave*256 floats (4 rows)
  const int bh = blockIdx.x;
  const int tau0 = blockIdx.y << 7;         // *128
  const int b = bh >> 3, h = bh & 7;
  const size_t gbase = (size_t)b * L_ * C_ + (size_t)h * 64;
  const int l16 = tid & 15;                 // float4 lane within a 64-e row
  const int rbase = tid >> 4;               // 0..31: row within a 32-row pass
  const int bp0 = 112 - slot16;             // wave-uniform (SGPR), in {0,16,...,112}

  float acc[16];
#pragma unroll
  for (int i = 0; i < 16; ++i) acc[i] = 0.f;

  const float* qp = Q + gbase + e;          // per-thread Q column base

  // prologue: K logical rows 0..159 (5 passes of 32) via DMA
#pragma unroll
  for (int it = 0; it < 5; ++it) {
    int l = it * 32 + rbase;
    int tk = (l - tau0 - 127 + 2048) & LMASK;
    gload16(K + gbase + (size_t)tk * C_ + l16 * 4, ks + it * 2048 + wb);
  }
  __syncthreads();                          // drains vmcnt -> LDS data visible

  int cph = 0;                              // (chunk*32) mod 192
  for (int chunk = 0; chunk < NCHUNK; ++chunk) {
    const int t0 = chunk * TC;
    // ---- issue async K staging for chunk+1 (lands during compute) --------
    if (chunk + 1 < NCHUNK) {
      const int l0 = t0 + 160;              // logical rows l0..l0+31
      int tk = (l0 + rbase - tau0 - 127 + 2048) & LMASK;
      int sp = cph + 160; if (sp >= CAP1) sp -= CAP1;  // 32-aligned, contiguous
      gload16(K + gbase + (size_t)tk * C_ + l16 * 4, ks + sp * 64 + wb);
    }
    const float* qc = qp + (size_t)t0 * C_;   // this chunk's q base (global)
    // ---- compute: two 16x16 register tiles over a 47-reg k-window --------
    int bp = bp0 + cph; if (bp >= CAP1) bp -= CAP1;     // wave-uniform (SGPR)
    float km[47];
    if (bp <= CAP1 - 31) {
#pragma unroll
      for (int m = 0; m < 31; ++m) km[m] = ks[(bp + m) * 64 + e];
    } else {
#pragma unroll
      for (int m = 0; m < 31; ++m) {
        int p = bp + m; if (p >= CAP1) p -= CAP1;
        km[m] = ks[p * 64 + e];
      }
    }
#pragma unroll
    for (int jt = 0; jt < 16; ++jt) {
      float qv = qc[(size_t)jt * C_];       // global scalar, L2-served
#pragma unroll
      for (int i = 0; i < 16; ++i) acc[i] = fmaf(qv, km[15 + jt - i], acc[i]);
    }
    if (bp <= CAP1 - 47) {
#pragma unroll
      for (int m = 31; m < 47; ++m) km[m] = ks[(bp + m) * 64 + e];
    } else {
#pragma unroll
      for (int m = 31; m < 47; ++m) {
        int p = bp + m; if (p >= CAP1) p -= CAP1;
        km[m] = ks[p * 64 + e];
      }
    }
#pragma unroll
    for (int jt = 16; jt < 32; ++jt) {
      float qv = qc[(size_t)jt * C_];
#pragma unroll
      for (int i = 0; i < 16; ++i) acc[i] = fmaf(qv, km[15 + jt - i], acc[i]);
    }
    __syncthreads();    // staged loads landed; window reads done for all waves
    cph += 32; if (cph >= CAP1) cph -= CAP1;
  }
  // transpose in LDS, coalesced write (tau-contiguous rows) ----------------
  float* wt = ks;  // 128*65 = 8320 floats <= 12288
#pragma unroll
  for (int i = 0; i < 16; ++i) wt[(slot16 + i) * 65 + e] = acc[i];
  __syncthreads();
  const int to = tid & 127;
  const size_t cbase = ((size_t)b * C_ + (size_t)h * 64) * LS + tau0 + to;
  for (int cr = tid >> 7; cr < 64; cr += 4)
    corr[cbase + (size_t)cr * LS] = wt[to * 65 + cr];
}

// ---------------------------------------------------------------------------
// K1 (S=2,4): pooled correlation, fp32 direct, register-tiled, circular-K.
// ---------------------------------------------------------------------------
template<int S>
__device__ __forceinline__ float4 pool_load(const float* gp) {
  float4 v = *(const float4*)gp;
  if constexpr (S >= 2) {
    float4 v2 = *(const float4*)(gp + C_);
    v.x += v2.x; v.y += v2.y; v.z += v2.z; v.w += v2.w;
  }
  if constexpr (S == 4) {
    float4 v3 = *(const float4*)(gp + 2 * C_);
    float4 v4 = *(const float4*)(gp + 3 * C_);
    v.x += v3.x + v4.x; v.y += v3.y + v4.y;
    v.z += v3.z + v4.z; v.w += v3.w + v4.w;
  }
  constexpr float sc = (S == 1) ? 1.f : (S == 2) ? 0.5f : 0.25f;
  if constexpr (S >= 2) { v.x *= sc; v.y *= sc; v.z *= sc; v.w *= sc; }
  return v;
}

template<int S>
__launch_bounds__(256, 3)
__global__ void k_corr(const float* __restrict__ Q, const float* __restrict__ K,
                       float* __restrict__ corr) {
  constexpr int LS = 1024 / S;
  constexpr int LMASK = LS - 1;
  constexpr int NCHUNK = LS / TC;
  __shared__ float qs[TC * 64];       // 8KB  [t_local][e]
  __shared__ float ks[CAPR * 64];     // 40KB circular [p][e]; reused for transpose
  const int tid = threadIdx.x;
  const int e = tid & 63;
  const int slot32 = __builtin_amdgcn_readfirstlane((tid >> 6) << 5);
  const int bh = blockIdx.x;
  const int tau0 = blockIdx.y << 7;         // *128
  const int b = bh >> 3, h = bh & 7;
  const size_t gbase = (size_t)b * L_ * C_ + (size_t)h * 64;
  const int l16 = tid & 15;                 // float4 lane within a 64-e row
  const int rbase = tid >> 4;               // 16 rows per staging iteration
  const int bp0 = 96 - slot32;              // wave-uniform, in {0,32,64,96}

  float acc[32];
#pragma unroll
  for (int i = 0; i < 32; ++i) acc[i] = 0.f;

  int cph = 0;                              // (chunk*32) mod 160
  for (int chunk = 0; chunk < NCHUNK; ++chunk) {
    const int t0 = chunk * TC;
    __syncthreads();                        // prev chunk's LDS reads done
    {
      // stage q: 32 rows
#pragma unroll
      for (int it = 0; it < 2; ++it) {
        int row = rbase + it * 16;
        int traw = (t0 + row) * S;
        float4 v = pool_load<S>(Q + gbase + (size_t)traw * C_ + l16 * 4);
        *(float4*)(qs + row * 64 + l16 * 4) = v;
      }
      if (chunk == 0) {
#pragma unroll
        for (int it = 0; it < 10; ++it) {
          int l = rbase + it * 16;
          int tk = (l - tau0 - 127 + 2048) & LMASK;
          float4 v = pool_load<S>(K + gbase + (size_t)tk * S * C_ + l16 * 4);
          *(float4*)(ks + l * 64 + l16 * 4) = v;
        }
      } else {
        int sp = cph + 128; if (sp >= CAPR) sp -= CAPR;
#pragma unroll
        for (int it = 0; it < 2; ++it) {
          int row = rbase + it * 16;
          int l = t0 + 128 + row;
          int tk = (l - tau0 - 127 + 2048) & LMASK;
          int p = sp + row; if (p >= CAPR) p -= CAPR;
          float4 v = pool_load<S>(K + gbase + (size_t)tk * S * C_ + l16 * 4);
          *(float4*)(ks + p * 64 + l16 * 4) = v;
        }
      }
      __syncthreads();
    }
    // ---- compute: two 16x32 register tiles over a 63-reg k-window
    int bp = bp0 + cph; if (bp >= CAPR) bp -= CAPR;   // wave-uniform
    float km[63];
    if (bp <= CAPR - 47) {
#pragma unroll
      for (int m = 0; m < 47; ++m) km[m] = ks[(bp + m) * 64 + e];
    } else {
#pragma unroll
      for (int m = 0; m < 47; ++m) {
        int p = bp + m; if (p >= CAPR) p -= CAPR;
        km[m] = ks[p * 64 + e];
      }
    }
#pragma unroll
    for (int jt = 0; jt < 16; ++jt) {
      float qv = qs[jt * 64 + e];
#pragma unroll
      for (int i = 0; i < 32; ++i) acc[i] = fmaf(qv, km[31 + jt - i], acc[i]);
    }
    if (bp <= CAPR - 63) {
#pragma unroll
      for (int m = 47; m < 63; ++m) km[m] = ks[(bp + m) * 64 + e];
    } else {
#pragma unroll
      for (int m = 47; m < 63; ++m) {
        int p = bp + m; if (p >= CAPR) p -= CAPR;
        km[m] = ks[p * 64 + e];
      }
    }
#pragma unroll
    for (int jt = 16; jt < 32; ++jt) {
      float qv = qs[jt * 64 + e];
#pragma unroll
      for (int i = 0; i < 32; ++i) acc[i] = fmaf(qv, km[31 + jt - i], acc[i]);
    }
    cph += 32; if (cph >= CAPR) cph -= CAPR;
  }
  // transpose in LDS, coalesced write (tau-contiguous rows) ----------------
  __syncthreads();
  float* wt = ks;  // 128*65 = 8320 floats <= 10240
#pragma unroll
  for (int i = 0; i < 32; ++i) wt[(slot32 + i) * 65 + e] = acc[i];
  __syncthreads();
  const int to = tid & 127;
  const size_t cbase = ((size_t)b * C_ + (size_t)h * 64) * LS + tau0 + to;
  for (int cr = tid >> 7; cr < 64; cr += 2)
    corr[cbase + (size_t)cr * LS] = wt[to * 65 + cr];
}

// ---------------------------------------------------------------------------
// K2 (merged scales): per-(scale,b) stats, cm partials, peak detect +
// compaction (one global atomic per block) + level-0 histogram.
// Grid: (C_/GCH, B, 3).
// ---------------------------------------------------------------------------
__launch_bounds__(256, 4)
__global__ void k_stats(const float* __restrict__ corrbase, float* __restrict__ cm,
                        double* s1, double* s2, u32* peak_cnt, u32* histA,
                        u32* pkbase) {
  __shared__ __align__(16) float rows[GCH * 1024];
  __shared__ u32 hist_s[256];
  __shared__ double red_d[8];
  __shared__ u32 wv[4], wbase[4];
  const int tid = threadIdx.x;
  const int sidx = blockIdx.z;
  const int b = blockIdx.y;
  const int sb = sidx * 16 + b;
  const int Ls = 1024 >> sidx;
  const int c0 = blockIdx.x * GCH;
  const int lane = tid & 63;
  const int wave = tid >> 6;
  hist_s[tid] = 0;
  {
    const float4* src4 =
        (const float4*)(corrbase + co(sidx) + ((size_t)b * C_ + c0) * Ls);
    float4* dst4 = (float4*)rows;
    const int n4 = GCH * Ls / 4;
    for (int i = tid; i < n4; i += 256) dst4[i] = src4[i];
  }
  __syncthreads();
  const int nt = Ls >> 8;         // taus per thread: 4/2/1
  float cmacc[4] = {0.f, 0.f, 0.f, 0.f};
  double ls1 = 0.0, ls2 = 0.0;
  u32 mycnt = 0;
  // ---- phase 1: stats + peak count + level-0 hist
  for (int g = 0; g < GCH; ++g) {
    const float* row = rows + g * Ls;
    for (int i = 0; i < nt; ++i) {
      int t = tid + (i << 8);
      float v = row[t];
      cmacc[i] += v;
      ls1 += (double)v;
      ls2 += (double)v * (double)v;
      bool pk = (t >= 1) && (t <= Ls - 2) && (v > row[t - 1]) && (v > row[t + 1]);
      if (pk) {
        ++mycnt;
        atomicAdd(&hist_s[f2key(v) >> 24], 1u);
      }
    }
  }
  // block-scan peak counts -> single global atomic for base
  u32 wc = mycnt;
  for (int off = 32; off; off >>= 1) wc += __shfl_down(wc, off, 64);
  if (lane == 0) wv[wave] = wc;
  __syncthreads();
  if (tid == 0) {
    u32 t = 0;
    for (int w = 0; w < 4; ++w) { wbase[w] = t; t += wv[w]; }
    u32 base = atomicAdd(&peak_cnt[sb * 16], t);
    for (int w = 0; w < 4; ++w) wbase[w] += base;
  }
  __syncthreads();
  // ---- phase 2: re-detect, compacted write at deterministic offsets
  const u32 cap = pk_cap(sidx);
  u32* dst_pk = pkbase + pk_off(sidx) + (u32)b * cap;
  u32 off_w = wbase[wave];
  const u64 below = (1ull << lane) - 1ull;
  for (int g = 0; g < GCH; ++g) {
    const float* row = rows + g * Ls;
    for (int i = 0; i < nt; ++i) {
      int t = tid + (i << 8);
      float v = row[t];
      bool pk = (t >= 1) && (t <= Ls - 2) && (v > row[t - 1]) && (v > row[t + 1]);
      u64 mask = __ballot(pk);
      if (pk) {
        u32 idx = off_w + (u32)__popcll(mask & below);
        if (idx < cap) dst_pk[idx] = f2key(v);
      }
      off_w += (u32)__popcll(mask);
    }
  }
  // cm partials: one unsafe float atomic per owned tau
  for (int i = 0; i < nt; ++i) {
    int t = tid + (i << 8);
    unsafeAtomicAdd(&cm[sb * 1024 + t], cmacc[i]);
  }
  // s1/s2: wave reduce -> block reduce -> one double atomic per block
  for (int off = 32; off; off >>= 1) {
    ls1 += __shfl_down(ls1, off, 64);
    ls2 += __shfl_down(ls2, off, 64);
  }
  if (lane == 0) { red_d[wave] = ls1; red_d[4 + wave] = ls2; }
  __syncthreads();
  if (tid == 0) {
    unsafeAtomicAdd(&s1[sb], red_d[0] + red_d[1] + red_d[2] + red_d[3]);
    unsafeAtomicAdd(&s2[sb], red_d[4] + red_d[5] + red_d[6] + red_d[7]);
  }
  if (hist_s[tid]) atomicAdd(&histA[sb * 256 + tid], hist_s[tid]);
}

// ---------------------------------------------------------------------------
// K3 (merged): one block per (scale,b). cm pk-count, MLP -> kvals, level-0
// radix scan (snapshot-then-write). Energy computed redundantly per block.
// ---------------------------------------------------------------------------
__global__ void k_mlp(const float* __restrict__ cm, const double* s1,
                      const double* s2, const u32* peak_cnt, const u32* histA,
                      int* rank_s, u32* prefix_s, u32* active, float* thresh,
                      const float* w1, const float* b1, const float* w2,
                      const float* b2, const float* w3, const float* b3) {
  __shared__ float wls[673];       // w1(96) b1(32) w2(512) b2(16) w3(16) b3(1)
  __shared__ float cmrow[1024];
  __shared__ int red_i[4];
  __shared__ u32 cum[256];
  const int tid = threadIdx.x;
  const int sb = blockIdx.x;
  const int sidx = sb >> 4;
  const int Ls = 1024 >> sidx;
  for (int i = tid; i < 96; i += 256) wls[i] = w1[i];
  for (int i = tid; i < 32; i += 256) wls[96 + i] = b1[i];
  for (int i = tid; i < 512; i += 256) wls[128 + i] = w2[i];
  if (tid < 16) wls[640 + tid] = b2[tid];
  if (tid < 16) wls[656 + tid] = w3[tid];
  if (tid == 0) wls[672] = b3[0];
  for (int i = tid; i < Ls; i += 256) cmrow[i] = cm[sb * 1024 + i];
  __syncthreads();
  int cnt = 0;
  for (int t = 1 + tid; t <= Ls - 2; t += 256) {
    float v = cmrow[t];
    cnt += (v > cmrow[t - 1]) && (v > cmrow[t + 1]);
  }
  for (int off = 32; off; off >>= 1) cnt += __shfl_down(cnt, off, 64);
  if ((tid & 63) == 0) red_i[tid >> 6] = cnt;
  __syncthreads();
  if (tid == 0) {
    double tot = 0.0;
    for (int j = 0; j < 16; ++j) tot += s2[sidx * 16 + j];
    float f0 = (float)(tot / (16.0 * (double)Ls));
    double N = (double)C_ * (double)Ls;
    float f1 = (float)((s2[sb] - s1[sb] * s1[sb] / N) / (N - 1.0));
    float f2 = (float)(red_i[0] + red_i[1] + red_i[2] + red_i[3]);
    float h1[32];
    for (int j = 0; j < 32; ++j)
      h1[j] = fmaxf(0.f, wls[j * 3] * f0 + wls[j * 3 + 1] * f1 + wls[j * 3 + 2] * f2 + wls[96 + j]);
    float h2[16];
    for (int j = 0; j < 16; ++j) {
      float a = wls[640 + j];
      for (int i = 0; i < 32; ++i) a += wls[128 + j * 32 + i] * h1[i];
      h2[j] = fmaxf(0.f, a);
    }
    float z = wls[672];
    for (int i = 0; i < 16; ++i) z += wls[656 + i] * h2[i];
    float ratio = 1.0f / (1.0f + __expf(-z));
    int kv = (int)(ratio * (float)Ls);
    kv = min(max(kv, 1), Ls);
    int cntb = (int)peak_cnt[sb * 16];
    active[sb] = (u32)(cntb > kv);
    thresh[sb] = -INFINITY;
    rank_s[sb] = kv;
    prefix_s[sb] = 0;
  }
  __syncthreads();
  // level-0 radix scan: parallel suffix-scan over 256 bins
  cum[tid] = histA[sb * 256 + tid];
  __syncthreads();
  for (int off = 1; off < 256; off <<= 1) {
    u32 add = (tid + off < 256) ? cum[tid + off] : 0u;
    __syncthreads();
    cum[tid] += add;
    __syncthreads();
  }
  u32 act_b = active[sb];
  u32 r = act_b ? (u32)rank_s[sb] : 0u;
  u32 cc = cum[tid];
  u32 cnext = (tid == 255) ? 0u : cum[tid + 1];
  __syncthreads();          // all snapshots done before any write
  if (act_b && r > 0 && cc >= r && cnext < r) {
    prefix_s[sb] = (u32)tid << 24;
    rank_s[sb] = (int)(r - cnext);
  }
}

// ---------------------------------------------------------------------------
// K_sel (levels 1..3): full key scan, LDS->global hist, ticket finisher does
// the parallel suffix-scan + snapshot-write refine. Grid: 3*16*NB_SEL.
// ---------------------------------------------------------------------------
__global__ void k_sel(const u32* __restrict__ pkbase, const u32* peak_cnt,
                      const u32* active, int* rank_s, u32* prefix_s,
                      u32* hist, u32* done, float* thresh, int level) {
  __shared__ u32 hist_s[256];
  __shared__ u32 cum[256];
  __shared__ u32 islast;
  const int tid = threadIdx.x;
  const int sb = blockIdx.x / NB_SEL;
  const int blk = blockIdx.x % NB_SEL;
  const int sidx = sb >> 4;
  hist_s[tid] = 0;
  if (tid == 0) islast = 0;
  __syncthreads();
  const int act = (int)active[sb];
  const u32 cap = pk_cap(sidx);
  u32 cnt = peak_cnt[sb * 16];
  if (cnt > cap) cnt = cap;
  if (act) {
    const u32 pref = prefix_s[sb];
    const int hi_sh = 32 - 8 * level;
    const int b_sh = 24 - 8 * level;
    const u32 lo = (u32)(((u64)cnt * (u64)blk) / NB_SEL);
    const u32 hi = (u32)(((u64)cnt * (u64)(blk + 1)) / NB_SEL);
    const u32* src = pkbase + pk_off(sidx) + (u32)(sb & 15) * cap;
    for (u32 i = lo + tid; i < hi; i += 256) {
      u32 key = src[i];
      if ((key >> hi_sh) == (pref >> hi_sh))
        atomicAdd(&hist_s[(key >> b_sh) & 255u], 1u);
    }
  }
  __syncthreads();
  if (hist_s[tid]) atomicAdd(&hist[sb * 256 + tid], hist_s[tid]);
  __syncthreads();                        // barrier drains all vmem (vmcnt(0))
  if (tid == 0) {
    __threadfence();
    u32 t = atomicAdd(&done[(level - 1) * 48 + sb], 1u);
    if (t == NB_SEL - 1) islast = 1;
  }
  __syncthreads();
  if (!islast) return;
  // ---- finisher (exactly one block per (scale,b))
  __threadfence();
  u32 hv = atomicAdd(&hist[sb * 256 + tid], 0u);    // atomic read
  cum[tid] = hv;
  hist[sb * 256 + tid] = 0;               // ready for next level
  __syncthreads();
  for (int off = 1; off < 256; off <<= 1) {
    u32 add = (tid + off < 256) ? cum[tid + off] : 0u;
    __syncthreads();
    cum[tid] += add;
    __syncthreads();
  }
  u32 r = act ? (u32)rank_s[sb] : 0u;
  u32 pref2 = act ? prefix_s[sb] : 0u;
  u32 cc = cum[tid];
  u32 cnext = (tid == 255) ? 0u : cum[tid + 1];
  __syncthreads();                        // snapshots before write
  if (act && r > 0 && cc >= r && cnext < r) {
    u32 np = pref2 | ((u32)tid << (24 - 8 * level));
    prefix_s[sb] = np;
    rank_s[sb] = (int)(r - cnext);
    if (level == 3) thresh[sb] = key2f(np);
  }
}

// ---------------------------------------------------------------------------
// K5a (merged): per-(scale,b,c) softmax stats. Grid: (8192, 3).
// ---------------------------------------------------------------------------
__global__ void k_softstats(const float* __restrict__ corrbase, const float* thresh,
                            float2* __restrict__ mZ) {
  __shared__ float row[1024];
  __shared__ float red_s[8];
  const int tid = threadIdx.x;
  const int bc = blockIdx.x;
  const int sidx = blockIdx.y;
  const int Ls = 1024 >> sidx;
  const float th = thresh[sidx * 16 + (bc >> 9)];
  const float* src = corrbase + co(sidx) + (size_t)bc * Ls;
  for (int t = tid; t < Ls; t += 256) row[t] = src[t];
  __syncthreads();
  float mx = 0.f;   // zeros always present in attn row -> true max >= 0
  for (int t = tid; t < Ls; t += 256) {
    float v = row[t];
    bool pk = (t >= 1) && (t <= Ls - 2) && (v > row[t - 1]) && (v > row[t + 1]) && (v >= th);
    if (pk) mx = fmaxf(mx, v);
  }
  for (int off = 32; off; off >>= 1) mx = fmaxf(mx, __shfl_down(mx, off, 64));
  if ((tid & 63) == 0) red_s[tid >> 6] = mx;
  __syncthreads();
  float m = fmaxf(fmaxf(red_s[0], red_s[1]), fmaxf(red_s[2], red_s[3]));
  float zs = 0.f;
  for (int t = tid; t < Ls; t += 256) {
    float v = row[t];
    bool pk = (t >= 1) && (t <= Ls - 2) && (v > row[t - 1]) && (v > row[t + 1]) && (v >= th);
    float a = pk ? v : 0.f;
    zs += __expf(a - m);
  }
  for (int off = 32; off; off >>= 1) zs += __shfl_down(zs, off, 64);
  if ((tid & 63) == 0) red_s[4 + (tid >> 6)] = zs;
  __syncthreads();
  if (tid == 0) {
    float Z = red_s[4] + red_s[5] + red_s[6] + red_s[7];
    mZ[sidx * 8192 + bc] = make_float2(m, 1.0f / Z);
  }
}

// ---------------------------------------------------------------------------
// K5b (s=2,4): o_s[b][tau][c] = softmax-weight * pooled v. 128-tau tiles.
// corr/mZ/thresh passed pre-offset for the scale.
// ---------------------------------------------------------------------------
__launch_bounds__(256, 4)
__global__ void k_apply(const float* __restrict__ corr, const float* __restrict__ V,
                        const float2* __restrict__ mZ, const float* thresh,
                        float* __restrict__ o, int Ls, int s) {
  __shared__ float ct[64][131];      // col j holds t = t0-1+j (clamped)
  __shared__ float m_s[64], rz_s[64];
  const int tid = threadIdx.x;
  const int b = blockIdx.z;
  const int c0 = blockIdx.y << 6;
  const int t0 = blockIdx.x << 7;
  {
    const int row0 = tid >> 7, jc = tid & 127;
    for (int rr = row0; rr < 64; rr += 2) {
      const float* src = corr + ((size_t)b * C_ + c0 + rr) * Ls;
      for (int j = jc; j < 130; j += 128) {
        int t = t0 - 1 + j;
        t = max(0, min(t, Ls - 1));
        ct[rr][j] = src[t];
      }
    }
  }
  if (tid < 64) {
    float2 v = mZ[b * C_ + c0 + tid];
    m_s[tid] = v.x; rz_s[tid] = v.y;
  }
  __syncthreads();
  const float th = thresh[b];
  const int cl = tid & 63, ts = tid >> 6;
  for (int ii = 0; ii < 32; ++ii) {
    int tl = ts + (ii << 2);
    int tg = t0 + tl;
    float vm = ct[cl][tl], vc = ct[cl][tl + 1], vp = ct[cl][tl + 2];
    bool pk = (tg >= 1) && (tg <= Ls - 2) && (vc > vm) && (vc > vp) && (vc >= th);
    float a = pk ? vc : 0.f;
    float w = __expf(a - m_s[cl]) * rz_s[cl];
    size_t vb = ((size_t)b * L_ + (size_t)tg * s) * C_ + c0 + cl;
    float vv;
    if (s == 2) vv = (V[vb] + V[vb + C_]) * 0.5f;
    else vv = ((V[vb] + V[vb + C_]) + (V[vb + 2 * C_] + V[vb + 3 * C_])) * 0.25f;
    o[((size_t)b * Ls + tg) * C_ + c0 + cl] = w * vv;
  }
}

// ---------------------------------------------------------------------------
// K5b-final (s=1): out = sw0*w*v + sw1*lerp(o2) + sw2*lerp(o4). 128-tau tiles.
// ---------------------------------------------------------------------------
__launch_bounds__(256, 4)
__global__ void k_apply_final(const float* __restrict__ corr, const float* __restrict__ V,
                              const float2* __restrict__ mZ, const float* thresh,
                              const float* __restrict__ o2, const float* __restrict__ o4,
                              const float* __restrict__ sw, float* __restrict__ out) {
  __shared__ float ct[64][131];
  __shared__ float m_s[64], rz_s[64];
  const int Ls = 1024;
  const int tid = threadIdx.x;
  const int b = blockIdx.z;
  const int c0 = blockIdx.y << 6;
  const int t0 = blockIdx.x << 7;
  {
    const int row0 = tid >> 7, jc = tid & 127;
    for (int rr = row0; rr < 64; rr += 2) {
      const float* src = corr + ((size_t)b * C_ + c0 + rr) * Ls;
      for (int j = jc; j < 130; j += 128) {
        int t = t0 - 1 + j;
        t = max(0, min(t, Ls - 1));
        ct[rr][j] = src[t];
      }
    }
  }
  if (tid < 64) {
    float2 v = mZ[b * C_ + c0 + tid];
    m_s[tid] = v.x; rz_s[tid] = v.y;
  }
  __syncthreads();
  const float th = thresh[b];
  const float sw0 = sw[0], sw1 = sw[1], sw2 = sw[2];
  const int cl = tid & 63, ts = tid >> 6;
  for (int ii = 0; ii < 32; ++ii) {
    int tl = ts + (ii << 2);
    int tg = t0 + tl;
    float vm = ct[cl][tl], vc = ct[cl][tl + 1], vp = ct[cl][tl + 2];
    bool pk = (tg >= 1) && (tg <= Ls - 2) && (vc > vm) && (vc > vp) && (vc >= th);
    float a = pk ? vc : 0.f;
    float w = __expf(a - m_s[cl]) * rz_s[cl];
    float v1 = V[((size_t)b * L_ + tg) * C_ + c0 + cl];
    float r = sw0 * w * v1;
    {
      float srcp = fmaxf((tg + 0.5f) * 0.5f - 0.5f, 0.f);
      int x0 = (int)srcp;
      float lam = srcp - (float)x0;
      int x1 = min(x0 + 1, 511);
      const float* p = o2 + (size_t)b * 512 * C_ + c0 + cl;
      r += sw1 * ((1.f - lam) * p[(size_t)x0 * C_] + lam * p[(size_t)x1 * C_]);
    }
    {
      float srcp = fmaxf((tg + 0.5f) * 0.25f - 0.5f, 0.f);
      int x0 = (int)srcp;
      float lam = srcp - (float)x0;
      int x1 = min(x0 + 1, 255);
      const float* p = o4 + (size_t)b * 256 * C_ + c0 + cl;
      r += sw2 * ((1.f - lam) * p[(size_t)x0 * C_] + lam * p[(size_t)x1 * C_]);
    }
    out[((size_t)b * L_ + tg) * C_ + c0 + cl] = r;
  }
}

// ---------------------------------------------------------------------------
extern "C" void kernel_launch(void* const* d_in, const int* in_sizes, int n_in,
                              void* d_out, int out_size, void* d_ws, size_t ws_size,
                              hipStream_t stream) {
  const float* Q  = (const float*)d_in[0];
  const float* Kk = (const float*)d_in[1];
  const float* V  = (const float*)d_in[2];
  const float* sw = (const float*)d_in[3];
  const float* w1 = (const float*)d_in[4];
  const float* b1 = (const float*)d_in[5];
  const float* w2 = (const float*)d_in[6];
  const float* b2 = (const float*)d_in[7];
  const float* w3 = (const float*)d_in[8];
  const float* b3 = (const float*)d_in[9];
  float* out = (float*)d_out;

  char* ws = (char*)d_ws;
  size_t p = 0;
  auto alloc = [&](size_t n) { char* r = ws + p; p = (p + n + 255) & ~(size_t)255; return r; };
  // corr for all 3 scales: [s1 | s2 | s4], elem offsets 0 / 8388608 / 12582912
  float*  corr = (float*)alloc((size_t)(8388608 + 4194304 + 2097152) * 4);  // 58.7 MB
  // o-region: o2 (16.8MB) + o4 (8.4MB); pk_buf (22.5MB) aliases it (pk dies
  // after k_sel level 3; o2/o4 born at k_apply, strictly later in-stream).
  char*   oreg = alloc((size_t)25165824);
  float*  o2   = (float*)oreg;
  float*  o4   = (float*)(oreg + 16777216);
  u32*    pk   = (u32*)oreg;
  float*  cm       = (float*)alloc(3 * 16 * 1024 * 4);
  float2* mZ       = (float2*)alloc(3 * 16 * 512 * 8);
  double* s1d      = (double*)alloc(48 * 8);
  double* s2d      = (double*)alloc(48 * 8);
  u32*    histA    = (u32*)alloc(3 * 16 * 256 * 4);
  u32*    histB    = (u32*)alloc(3 * 16 * 256 * 4);
  u32*    peak_cnt = (u32*)alloc(3 * 16 * 16 * 4);   // padded: 1 counter / 64B
  u32*    done     = (u32*)alloc(144 * 4);
  int*    rank_s   = (int*)alloc(48 * 4);
  u32*    prefix_s = (u32*)alloc(48 * 4);
  u32*    active   = (u32*)alloc(48 * 4);
  float*  thresh   = (float*)alloc(48 * 4);

  k_init<<<dim3(16), dim3(256), 0, stream>>>(histA, histB, peak_cnt, done,
                                             s1d, s2d, cm);
  k_corr1<<<dim3(128, 8), dim3(512), 0, stream>>>(Q, Kk, corr);
  k_corr<2><<<dim3(128, 4), dim3(256), 0, stream>>>(Q, Kk, corr + 8388608);
  k_corr<4><<<dim3(128, 2), dim3(256), 0, stream>>>(Q, Kk, corr + 12582912);
  k_stats<<<dim3(C_ / GCH, B_, 3), dim3(256), 0, stream>>>(
      corr, cm, s1d, s2d, peak_cnt, histA, pk);
  k_mlp<<<dim3(48), dim3(256), 0, stream>>>(
      cm, s1d, s2d, peak_cnt, histA, rank_s, prefix_s, active, thresh,
      w1, b1, w2, b2, w3, b3);
  for (int level = 1; level <= 3; ++level)
    k_sel<<<dim3(48 * NB_SEL), dim3(256), 0, stream>>>(
        pk, peak_cnt, active, rank_s, prefix_s, histB, done, thresh, level);
  k_softstats<<<dim3(8192, 3), dim3(256), 0, stream>>>(corr, thresh, mZ);
  k_apply<<<dim3(2, 8, 16), dim3(256), 0, stream>>>(
      corr + 12582912, V, mZ + 2 * 8192, thresh + 32, o4, 256, 4);
  k_apply<<<dim3(4, 8, 16), dim3(256), 0, stream>>>(
      corr + 8388608, V, mZ + 1 * 8192, thresh + 16, o2, 512, 2);
  k_apply_final<<<dim3(8, 8, 16), dim3(256), 0, stream>>>(
      corr, V, mZ, thresh, o2, o4, sw, out);
}

// Round 6
// 808.061 us; speedup vs baseline: 1.1484x; 1.1484x over previous
//
#include <hip/hip_runtime.h>
#include <math.h>

typedef unsigned int u32;
typedef unsigned long long u64;
typedef float f4 __attribute__((ext_vector_type(4)));

#define B_ 16
#define L_ 1024
#define H_ 8
#define E_ 64
#define C_ 512            // H_*E_
#define NB_SEL 8          // blocks per (scale,b) in k_sel
#define GCH 8             // channels per k_stats block
#define TC 32             // k_corr time-chunk
#define CAPR 160          // k_corr<S> circular K-buffer rows (= 127 + TC + 1)
#define CAP1 192          // k_corr1 ring rows (mod-192 ring, as r2)
#define KW 256            // k_corr1 K^T row width: 192 ring + 64 dup/pad image
#define QW 32             // k_corr1 q^T row width

// scale indexing: sidx 0 -> s=1 (Ls=1024), 1 -> s=2 (512), 2 -> s=4 (256)
__device__ __forceinline__ size_t co(int sidx) {       // corr elem offset
  return sidx == 0 ? 0u : (sidx == 1 ? 8388608u : 12582912u);
}
__device__ __forceinline__ u32 pk_off(int sidx) {      // pk elem offset in o-region
  return sidx == 0 ? 0u : (sidx == 1 ? 3211264u : 4816896u);
}
__device__ __forceinline__ u32 pk_cap(int sidx) { return 200704u >> sidx; }

__device__ __forceinline__ u32 f2key(float f) {
  u32 u = __float_as_uint(f);
  return (u & 0x80000000u) ? ~u : (u | 0x80000000u);
}
__device__ __forceinline__ float key2f(u32 k) {
  u32 u = (k & 0x80000000u) ? (k ^ 0x80000000u) : ~k;
  return __uint_as_float(u);
}

// ---------------------------------------------------------------------------
// K_init: zero control state once (single-pass pipeline -> no mid-run resets)
// ---------------------------------------------------------------------------
__global__ void k_init(u32* histA, u32* histB, u32* peak_cnt, u32* done,
                       double* s1, double* s2, float* cm) {
  const int gid = blockIdx.x * 256 + threadIdx.x;
  const int gs = gridDim.x * 256;
  for (int i = gid; i < 3 * 16 * 256; i += gs) { histA[i] = 0; histB[i] = 0; }
  for (int i = gid; i < 3 * 16 * 1024; i += gs) cm[i] = 0.f;
  for (int i = gid; i < 3 * 16 * 16; i += gs) peak_cnt[i] = 0;
  for (int i = gid; i < 144; i += gs) done[i] = 0;
  for (int i = gid; i < 48; i += gs) { s1[i] = 0.0; s2[i] = 0.0; }
}

// ---------------------------------------------------------------------------
// K1-S1: circular cross-correlation, fp32 direct, register-tiled.
// r2's proven 512-thread / 8-wave / 16-tau-per-wave structure and indexing,
// with BOTH LDS tiles transposed to [e][p] so every LDS read is b128:
//  - ksT[64][256]: mod-192 ring + rows 0..46 duplicated at 192..238 so km
//    window reads never wrap; XOR swizzle (p ^= 4*(e&7)) on 16B groups ->
//    2-way banks (free). km = 12 ds_read_b128 (was 47 b32).
//  - qT[2][64][32]: double buffer, same swizzle. q = 8 b128 (was 32 b32).
//  - LDS/wave-chunk 458 -> ~267 cyc => ~114us/CU, balanced vs FMA 109us.
//  - staging is reg-staged (transpose forbids global_load_lds): 8 coalesced
//    scalar global loads issued at chunk top, ds_write_b128 after compute,
//    ONE barrier per chunk (stage region & q buf^1 disjoint from live reads).
//  - LDS 80KB -> 2 blocks/CU = 4 waves/SIMD; launch_bounds(512,4) caps VGPR
//    at 128 vs ~91 live: clear of the r0/r4 (AGPR) and r5 (scratch) cliffs.
// ---------------------------------------------------------------------------
__launch_bounds__(512, 4)
__global__ void k_corr1(const float* __restrict__ Q, const float* __restrict__ K,
                        float* __restrict__ corr) {
  constexpr int LS = 1024;
  constexpr int LMASK = LS - 1;
  constexpr int NCHUNK = LS / TC;     // 32
  __shared__ __align__(16) float ksT[64 * KW];      // 64KB [e][p']
  __shared__ __align__(16) float qT[2 * 64 * QW];   // 16KB [buf][e][t']
  const int tid = threadIdx.x;        // 0..511
  const int e = tid & 63;
  const int w = tid >> 6;             // wave 0..7
  const int slot16 = __builtin_amdgcn_readfirstlane(w << 4);
  const int bh = blockIdx.x;
  const int tau0 = blockIdx.y << 7;         // *128
  const int b = bh >> 3, h = bh & 7;
  const size_t gbase = (size_t)b * L_ * C_ + (size_t)h * 64;
  const int x4 = (e & 7) << 2;              // 16B-group XOR swizzle
  const int bp0 = 112 - slot16;             // wave-uniform, in {0,16,...,112}
  float* krow = ksT + e * KW;
  float* qrow0 = qT + e * QW;
  float* qrow1 = qT + 2048 + e * QW;

  float acc[16];
#pragma unroll
  for (int i = 0; i < 16; ++i) acc[i] = 0.f;

  // prologue: K logical rows 0..159 at ring p=l (5 passes of 32 rows);
  // q rows 0..31 into buf0. All transposed + swizzled, b128 writes.
#pragma unroll
  for (int pass = 0; pass < 5; ++pass) {
    const int p0 = pass * 32 + (w << 2);
    f4 v;
#pragma unroll
    for (int j = 0; j < 4; ++j) {
      int tk = (p0 + j - tau0 - 127 + 2048) & LMASK;
      v[j] = K[gbase + (size_t)tk * C_ + e];
    }
    *(f4*)&krow[p0 ^ x4] = v;
    if (p0 < 47) *(f4*)&krow[(p0 + 192) ^ x4] = v;   // wrap image
  }
  {
    f4 v;
#pragma unroll
    for (int j = 0; j < 4; ++j)
      v[j] = Q[gbase + (size_t)((w << 2) + j) * C_ + e];
    *(f4*)&qrow0[(w << 2) ^ x4] = v;
  }
  __syncthreads();

  int cph = 0;                              // (chunk*32) mod 192
  for (int chunk = 0; chunk < NCHUNK; ++chunk) {
    const int t0 = chunk * TC;
    const bool more = (chunk + 1 < NCHUNK);
    // ---- issue global loads for chunk+1 (latency hides under compute) ----
    f4 kr, qr;
    int spw = 0;
    if (more) {
      int sp = cph + 160; if (sp >= CAP1) sp -= CAP1;  // 32-aligned
      spw = sp + (w << 2);                             // <= 188, no wrap
#pragma unroll
      for (int j = 0; j < 4; ++j) {
        int l = t0 + 160 + (w << 2) + j;
        int tk = (l - tau0 - 127 + 2048) & LMASK;
        kr[j] = K[gbase + (size_t)tk * C_ + e];
      }
#pragma unroll
      for (int j = 0; j < 4; ++j)
        qr[j] = Q[gbase + (size_t)(t0 + TC + (w << 2) + j) * C_ + e];
    }
    // ---- compute: 16 taus x 32 jt over a 47-row k-window, all b128 -------
    int bp = bp0 + cph; if (bp >= CAP1) bp -= CAP1;    // wave-uniform, 16-aligned
    f4 km4[12];                                        // rows bp..bp+47
#pragma unroll
    for (int j = 0; j < 12; ++j)
      km4[j] = *(const f4*)&krow[(bp + 4 * j) ^ x4];   // dup covers >=192
    const float* qb = (chunk & 1) ? qrow1 : qrow0;
#pragma unroll
    for (int g = 0; g < 8; ++g) {
      f4 qv = *(const f4*)&qb[(g << 2) ^ x4];
#pragma unroll
      for (int k = 0; k < 4; ++k) {
        const int jt = (g << 2) + k;
#pragma unroll
        for (int i = 0; i < 16; ++i) {
          const int m = 15 + jt - i;                   // 0..46, compile-time
          acc[i] = fmaf(qv[k], km4[m >> 2][m & 3], acc[i]);
        }
      }
    }
    // ---- write staged data (disjoint from all live read windows) ---------
    if (more) {
      *(f4*)&krow[spw ^ x4] = kr;
      if (spw < 47) *(f4*)&krow[(spw + 192) ^ x4] = kr;
      float* qn = (chunk & 1) ? qrow0 : qrow1;
      *(f4*)&qn[(w << 2) ^ x4] = qr;
    }
    __syncthreads();    // staged writes visible before next chunk's reads
    cph += 32; if (cph >= CAP1) cph -= CAP1;
  }
  // transpose in LDS, coalesced write (tau-contiguous rows) ----------------
  float* wt = ksT;  // 128*65 = 8320 floats <= 16384
#pragma unroll
  for (int i = 0; i < 16; ++i) wt[(slot16 + i) * 65 + e] = acc[i];
  __syncthreads();
  const int to = tid & 127;
  const size_t cbase = ((size_t)b * C_ + (size_t)h * 64) * LS + tau0 + to;
  for (int cr = tid >> 7; cr < 64; cr += 4)
    corr[cbase + (size_t)cr * LS] = wt[to * 65 + cr];
}

// ---------------------------------------------------------------------------
// K1 (S=2,4): pooled correlation, fp32 direct, register-tiled, circular-K.
// ---------------------------------------------------------------------------
template<int S>
__device__ __forceinline__ float4 pool_load(const float* gp) {
  float4 v = *(const float4*)gp;
  if constexpr (S >= 2) {
    float4 v2 = *(const float4*)(gp + C_);
    v.x += v2.x; v.y += v2.y; v.z += v2.z; v.w += v2.w;
  }
  if constexpr (S == 4) {
    float4 v3 = *(const float4*)(gp + 2 * C_);
    float4 v4 = *(const float4*)(gp + 3 * C_);
    v.x += v3.x + v4.x; v.y += v3.y + v4.y;
    v.z += v3.z + v4.z; v.w += v3.w + v4.w;
  }
  constexpr float sc = (S == 1) ? 1.f : (S == 2) ? 0.5f : 0.25f;
  if constexpr (S >= 2) { v.x *= sc; v.y *= sc; v.z *= sc; v.w *= sc; }
  return v;
}

template<int S>
__launch_bounds__(256, 3)
__global__ void k_corr(const float* __restrict__ Q, const float* __restrict__ K,
                       float* __restrict__ corr) {
  constexpr int LS = 1024 / S;
  constexpr int LMASK = LS - 1;
  constexpr int NCHUNK = LS / TC;
  __shared__ float qs[TC * 64];       // 8KB  [t_local][e]
  __shared__ float ks[CAPR * 64];     // 40KB circular [p][e]; reused for transpose
  const int tid = threadIdx.x;
  const int e = tid & 63;
  const int slot32 = __builtin_amdgcn_readfirstlane((tid >> 6) << 5);
  const int bh = blockIdx.x;
  const int tau0 = blockIdx.y << 7;         // *128
  const int b = bh >> 3, h = bh & 7;
  const size_t gbase = (size_t)b * L_ * C_ + (size_t)h * 64;
  const int l16 = tid & 15;                 // float4 lane within a 64-e row
  const int rbase = tid >> 4;               // 16 rows per staging iteration
  const int bp0 = 96 - slot32;              // wave-uniform, in {0,32,64,96}

  float acc[32];
#pragma unroll
  for (int i = 0; i < 32; ++i) acc[i] = 0.f;

  int cph = 0;                              // (chunk*32) mod 160
  for (int chunk = 0; chunk < NCHUNK; ++chunk) {
    const int t0 = chunk * TC;
    __syncthreads();                        // prev chunk's LDS reads done
    {
      // stage q: 32 rows
#pragma unroll
      for (int it = 0; it < 2; ++it) {
        int row = rbase + it * 16;
        int traw = (t0 + row) * S;
        float4 v = pool_load<S>(Q + gbase + (size_t)traw * C_ + l16 * 4);
        *(float4*)(qs + row * 64 + l16 * 4) = v;
      }
      if (chunk == 0) {
#pragma unroll
        for (int it = 0; it < 10; ++it) {
          int l = rbase + it * 16;
          int tk = (l - tau0 - 127 + 2048) & LMASK;
          float4 v = pool_load<S>(K + gbase + (size_t)tk * S * C_ + l16 * 4);
          *(float4*)(ks + l * 64 + l16 * 4) = v;
        }
      } else {
        int sp = cph + 128; if (sp >= CAPR) sp -= CAPR;
#pragma unroll
        for (int it = 0; it < 2; ++it) {
          int row = rbase + it * 16;
          int l = t0 + 128 + row;
          int tk = (l - tau0 - 127 + 2048) & LMASK;
          int p = sp + row; if (p >= CAPR) p -= CAPR;
          float4 v = pool_load<S>(K + gbase + (size_t)tk * S * C_ + l16 * 4);
          *(float4*)(ks + p * 64 + l16 * 4) = v;
        }
      }
      __syncthreads();
    }
    // ---- compute: two 16x32 register tiles over a 63-reg k-window
    int bp = bp0 + cph; if (bp >= CAPR) bp -= CAPR;   // wave-uniform
    float km[63];
    if (bp <= CAPR - 47) {
#pragma unroll
      for (int m = 0; m < 47; ++m) km[m] = ks[(bp + m) * 64 + e];
    } else {
#pragma unroll
      for (int m = 0; m < 47; ++m) {
        int p = bp + m; if (p >= CAPR) p -= CAPR;
        km[m] = ks[p * 64 + e];
      }
    }
#pragma unroll
    for (int jt = 0; jt < 16; ++jt) {
      float qv = qs[jt * 64 + e];
#pragma unroll
      for (int i = 0; i < 32; ++i) acc[i] = fmaf(qv, km[31 + jt - i], acc[i]);
    }
    if (bp <= CAPR - 63) {
#pragma unroll
      for (int m = 47; m < 63; ++m) km[m] = ks[(bp + m) * 64 + e];
    } else {
#pragma unroll
      for (int m = 47; m < 63; ++m) {
        int p = bp + m; if (p >= CAPR) p -= CAPR;
        km[m] = ks[p * 64 + e];
      }
    }
#pragma unroll
    for (int jt = 16; jt < 32; ++jt) {
      float qv = qs[jt * 64 + e];
#pragma unroll
      for (int i = 0; i < 32; ++i) acc[i] = fmaf(qv, km[31 + jt - i], acc[i]);
    }
    cph += 32; if (cph >= CAPR) cph -= CAPR;
  }
  // transpose in LDS, coalesced write (tau-contiguous rows) ----------------
  __syncthreads();
  float* wt = ks;  // 128*65 = 8320 floats <= 10240
#pragma unroll
  for (int i = 0; i < 32; ++i) wt[(slot32 + i) * 65 + e] = acc[i];
  __syncthreads();
  const int to = tid & 127;
  const size_t cbase = ((size_t)b * C_ + (size_t)h * 64) * LS + tau0 + to;
  for (int cr = tid >> 7; cr < 64; cr += 2)
    corr[cbase + (size_t)cr * LS] = wt[to * 65 + cr];
}

// ---------------------------------------------------------------------------
// K2 (merged scales): per-(scale,b) stats, cm partials, peak detect +
// compaction (one global atomic per block) + level-0 histogram.
// Grid: (C_/GCH, B, 3).
// ---------------------------------------------------------------------------
__launch_bounds__(256, 4)
__global__ void k_stats(const float* __restrict__ corrbase, float* __restrict__ cm,
                        double* s1, double* s2, u32* peak_cnt, u32* histA,
                        u32* pkbase) {
  __shared__ __align__(16) float rows[GCH * 1024];
  __shared__ u32 hist_s[256];
  __shared__ double red_d[8];
  __shared__ u32 wv[4], wbase[4];
  const int tid = threadIdx.x;
  const int sidx = blockIdx.z;
  const int b = blockIdx.y;
  const int sb = sidx * 16 + b;
  const int Ls = 1024 >> sidx;
  const int c0 = blockIdx.x * GCH;
  const int lane = tid & 63;
  const int wave = tid >> 6;
  hist_s[tid] = 0;
  {
    const float4* src4 =
        (const float4*)(corrbase + co(sidx) + ((size_t)b * C_ + c0) * Ls);
    float4* dst4 = (float4*)rows;
    const int n4 = GCH * Ls / 4;
    for (int i = tid; i < n4; i += 256) dst4[i] = src4[i];
  }
  __syncthreads();
  const int nt = Ls >> 8;         // taus per thread: 4/2/1
  float cmacc[4] = {0.f, 0.f, 0.f, 0.f};
  double ls1 = 0.0, ls2 = 0.0;
  u32 mycnt = 0;
  // ---- phase 1: stats + peak count + level-0 hist
  for (int g = 0; g < GCH; ++g) {
    const float* row = rows + g * Ls;
    for (int i = 0; i < nt; ++i) {
      int t = tid + (i << 8);
      float v = row[t];
      cmacc[i] += v;
      ls1 += (double)v;
      ls2 += (double)v * (double)v;
      bool pk = (t >= 1) && (t <= Ls - 2) && (v > row[t - 1]) && (v > row[t + 1]);
      if (pk) {
        ++mycnt;
        atomicAdd(&hist_s[f2key(v) >> 24], 1u);
      }
    }
  }
  // block-scan peak counts -> single global atomic for base
  u32 wc = mycnt;
  for (int off = 32; off; off >>= 1) wc += __shfl_down(wc, off, 64);
  if (lane == 0) wv[wave] = wc;
  __syncthreads();
  if (tid == 0) {
    u32 t = 0;
    for (int w = 0; w < 4; ++w) { wbase[w] = t; t += wv[w]; }
    u32 base = atomicAdd(&peak_cnt[sb * 16], t);
    for (int w = 0; w < 4; ++w) wbase[w] += base;
  }
  __syncthreads();
  // ---- phase 2: re-detect, compacted write at deterministic offsets
  const u32 cap = pk_cap(sidx);
  u32* dst_pk = pkbase + pk_off(sidx) + (u32)b * cap;
  u32 off_w = wbase[wave];
  const u64 below = (1ull << lane) - 1ull;
  for (int g = 0; g < GCH; ++g) {
    const float* row = rows + g * Ls;
    for (int i = 0; i < nt; ++i) {
      int t = tid + (i << 8);
      float v = row[t];
      bool pk = (t >= 1) && (t <= Ls - 2) && (v > row[t - 1]) && (v > row[t + 1]);
      u64 mask = __ballot(pk);
      if (pk) {
        u32 idx = off_w + (u32)__popcll(mask & below);
        if (idx < cap) dst_pk[idx] = f2key(v);
      }
      off_w += (u32)__popcll(mask);
    }
  }
  // cm partials: one unsafe float atomic per owned tau
  for (int i = 0; i < nt; ++i) {
    int t = tid + (i << 8);
    unsafeAtomicAdd(&cm[sb * 1024 + t], cmacc[i]);
  }
  // s1/s2: wave reduce -> block reduce -> one double atomic per block
  for (int off = 32; off; off >>= 1) {
    ls1 += __shfl_down(ls1, off, 64);
    ls2 += __shfl_down(ls2, off, 64);
  }
  if (lane == 0) { red_d[wave] = ls1; red_d[4 + wave] = ls2; }
  __syncthreads();
  if (tid == 0) {
    unsafeAtomicAdd(&s1[sb], red_d[0] + red_d[1] + red_d[2] + red_d[3]);
    unsafeAtomicAdd(&s2[sb], red_d[4] + red_d[5] + red_d[6] + red_d[7]);
  }
  if (hist_s[tid]) atomicAdd(&histA[sb * 256 + tid], hist_s[tid]);
}

// ---------------------------------------------------------------------------
// K3 (merged): one block per (scale,b). cm pk-count, MLP -> kvals, level-0
// radix scan (snapshot-then-write). Energy computed redundantly per block.
// ---------------------------------------------------------------------------
__global__ void k_mlp(const float* __restrict__ cm, const double* s1,
                      const double* s2, const u32* peak_cnt, const u32* histA,
                      int* rank_s, u32* prefix_s, u32* active, float* thresh,
                      const float* w1, const float* b1, const float* w2,
                      const float* b2, const float* w3, const float* b3) {
  __shared__ float wls[673];       // w1(96) b1(32) w2(512) b2(16) w3(16) b3(1)
  __shared__ float cmrow[1024];
  __shared__ int red_i[4];
  __shared__ u32 cum[256];
  const int tid = threadIdx.x;
  const int sb = blockIdx.x;
  const int sidx = sb >> 4;
  const int Ls = 1024 >> sidx;
  for (int i = tid; i < 96; i += 256) wls[i] = w1[i];
  for (int i = tid; i < 32; i += 256) wls[96 + i] = b1[i];
  for (int i = tid; i < 512; i += 256) wls[128 + i] = w2[i];
  if (tid < 16) wls[640 + tid] = b2[tid];
  if (tid < 16) wls[656 + tid] = w3[tid];
  if (tid == 0) wls[672] = b3[0];
  for (int i = tid; i < Ls; i += 256) cmrow[i] = cm[sb * 1024 + i];
  __syncthreads();
  int cnt = 0;
  for (int t = 1 + tid; t <= Ls - 2; t += 256) {
    float v = cmrow[t];
    cnt += (v > cmrow[t - 1]) && (v > cmrow[t + 1]);
  }
  for (int off = 32; off; off >>= 1) cnt += __shfl_down(cnt, off, 64);
  if ((tid & 63) == 0) red_i[tid >> 6] = cnt;
  __syncthreads();
  if (tid == 0) {
    double tot = 0.0;
    for (int j = 0; j < 16; ++j) tot += s2[sidx * 16 + j];
    float f0 = (float)(tot / (16.0 * (double)Ls));
    double N = (double)C_ * (double)Ls;
    float f1 = (float)((s2[sb] - s1[sb] * s1[sb] / N) / (N - 1.0));
    float f2 = (float)(red_i[0] + red_i[1] + red_i[2] + red_i[3]);
    float h1[32];
    for (int j = 0; j < 32; ++j)
      h1[j] = fmaxf(0.f, wls[j * 3] * f0 + wls[j * 3 + 1] * f1 + wls[j * 3 + 2] * f2 + wls[96 + j]);
    float h2[16];
    for (int j = 0; j < 16; ++j) {
      float a = wls[640 + j];
      for (int i = 0; i < 32; ++i) a += wls[128 + j * 32 + i] * h1[i];
      h2[j] = fmaxf(0.f, a);
    }
    float z = wls[672];
    for (int i = 0; i < 16; ++i) z += wls[656 + i] * h2[i];
    float ratio = 1.0f / (1.0f + __expf(-z));
    int kv = (int)(ratio * (float)Ls);
    kv = min(max(kv, 1), Ls);
    int cntb = (int)peak_cnt[sb * 16];
    active[sb] = (u32)(cntb > kv);
    thresh[sb] = -INFINITY;
    rank_s[sb] = kv;
    prefix_s[sb] = 0;
  }
  __syncthreads();
  // level-0 radix scan: parallel suffix-scan over 256 bins
  cum[tid] = histA[sb * 256 + tid];
  __syncthreads();
  for (int off = 1; off < 256; off <<= 1) {
    u32 add = (tid + off < 256) ? cum[tid + off] : 0u;
    __syncthreads();
    cum[tid] += add;
    __syncthreads();
  }
  u32 act_b = active[sb];
  u32 r = act_b ? (u32)rank_s[sb] : 0u;
  u32 cc = cum[tid];
  u32 cnext = (tid == 255) ? 0u : cum[tid + 1];
  __syncthreads();          // all snapshots done before any write
  if (act_b && r > 0 && cc >= r && cnext < r) {
    prefix_s[sb] = (u32)tid << 24;
    rank_s[sb] = (int)(r - cnext);
  }
}

// ---------------------------------------------------------------------------
// K_sel (levels 1..3): full key scan, LDS->global hist, ticket finisher does
// the parallel suffix-scan + snapshot-write refine. Grid: 3*16*NB_SEL.
// ---------------------------------------------------------------------------
__global__ void k_sel(const u32* __restrict__ pkbase, const u32* peak_cnt,
                      const u32* active, int* rank_s, u32* prefix_s,
                      u32* hist, u32* done, float* thresh, int level) {
  __shared__ u32 hist_s[256];
  __shared__ u32 cum[256];
  __shared__ u32 islast;
  const int tid = threadIdx.x;
  const int sb = blockIdx.x / NB_SEL;
  const int blk = blockIdx.x % NB_SEL;
  const int sidx = sb >> 4;
  hist_s[tid] = 0;
  if (tid == 0) islast = 0;
  __syncthreads();
  const int act = (int)active[sb];
  const u32 cap = pk_cap(sidx);
  u32 cnt = peak_cnt[sb * 16];
  if (cnt > cap) cnt = cap;
  if (act) {
    const u32 pref = prefix_s[sb];
    const int hi_sh = 32 - 8 * level;
    const int b_sh = 24 - 8 * level;
    const u32 lo = (u32)(((u64)cnt * (u64)blk) / NB_SEL);
    const u32 hi = (u32)(((u64)cnt * (u64)(blk + 1)) / NB_SEL);
    const u32* src = pkbase + pk_off(sidx) + (u32)(sb & 15) * cap;
    for (u32 i = lo + tid; i < hi; i += 256) {
      u32 key = src[i];
      if ((key >> hi_sh) == (pref >> hi_sh))
        atomicAdd(&hist_s[(key >> b_sh) & 255u], 1u);
    }
  }
  __syncthreads();
  if (hist_s[tid]) atomicAdd(&hist[sb * 256 + tid], hist_s[tid]);
  __syncthreads();                        // barrier drains all vmem (vmcnt(0))
  if (tid == 0) {
    __threadfence();
    u32 t = atomicAdd(&done[(level - 1) * 48 + sb], 1u);
    if (t == NB_SEL - 1) islast = 1;
  }
  __syncthreads();
  if (!islast) return;
  // ---- finisher (exactly one block per (scale,b))
  __threadfence();
  u32 hv = atomicAdd(&hist[sb * 256 + tid], 0u);    // atomic read
  cum[tid] = hv;
  hist[sb * 256 + tid] = 0;               // ready for next level
  __syncthreads();
  for (int off = 1; off < 256; off <<= 1) {
    u32 add = (tid + off < 256) ? cum[tid + off] : 0u;
    __syncthreads();
    cum[tid] += add;
    __syncthreads();
  }
  u32 r = act ? (u32)rank_s[sb] : 0u;
  u32 pref2 = act ? prefix_s[sb] : 0u;
  u32 cc = cum[tid];
  u32 cnext = (tid == 255) ? 0u : cum[tid + 1];
  __syncthreads();                        // snapshots before write
  if (act && r > 0 && cc >= r && cnext < r) {
    u32 np = pref2 | ((u32)tid << (24 - 8 * level));
    prefix_s[sb] = np;
    rank_s[sb] = (int)(r - cnext);
    if (level == 3) thresh[sb] = key2f(np);
  }
}

// ---------------------------------------------------------------------------
// K5a (merged): per-(scale,b,c) softmax stats. Grid: (8192, 3).
// ---------------------------------------------------------------------------
__global__ void k_softstats(const float* __restrict__ corrbase, const float* thresh,
                            float2* __restrict__ mZ) {
  __shared__ float row[1024];
  __shared__ float red_s[8];
  const int tid = threadIdx.x;
  const int bc = blockIdx.x;
  const int sidx = blockIdx.y;
  const int Ls = 1024 >> sidx;
  const float th = thresh[sidx * 16 + (bc >> 9)];
  const float* src = corrbase + co(sidx) + (size_t)bc * Ls;
  for (int t = tid; t < Ls; t += 256) row[t] = src[t];
  __syncthreads();
  float mx = 0.f;   // zeros always present in attn row -> true max >= 0
  for (int t = tid; t < Ls; t += 256) {
    float v = row[t];
    bool pk = (t >= 1) && (t <= Ls - 2) && (v > row[t - 1]) && (v > row[t + 1]) && (v >= th);
    if (pk) mx = fmaxf(mx, v);
  }
  for (int off = 32; off; off >>= 1) mx = fmaxf(mx, __shfl_down(mx, off, 64));
  if ((tid & 63) == 0) red_s[tid >> 6] = mx;
  __syncthreads();
  float m = fmaxf(fmaxf(red_s[0], red_s[1]), fmaxf(red_s[2], red_s[3]));
  float zs = 0.f;
  for (int t = tid; t < Ls; t += 256) {
    float v = row[t];
    bool pk = (t >= 1) && (t <= Ls - 2) && (v > row[t - 1]) && (v > row[t + 1]) && (v >= th);
    float a = pk ? v : 0.f;
    zs += __expf(a - m);
  }
  for (int off = 32; off; off >>= 1) zs += __shfl_down(zs, off, 64);
  if ((tid & 63) == 0) red_s[4 + (tid >> 6)] = zs;
  __syncthreads();
  if (tid == 0) {
    float Z = red_s[4] + red_s[5] + red_s[6] + red_s[7];
    mZ[sidx * 8192 + bc] = make_float2(m, 1.0f / Z);
  }
}

// ---------------------------------------------------------------------------
// K5b (s=2,4): o_s[b][tau][c] = softmax-weight * pooled v. 128-tau tiles.
// corr/mZ/thresh passed pre-offset for the scale.
// ---------------------------------------------------------------------------
__launch_bounds__(256, 4)
__global__ void k_apply(const float* __restrict__ corr, const float* __restrict__ V,
                        const float2* __restrict__ mZ, const float* thresh,
                        float* __restrict__ o, int Ls, int s) {
  __shared__ float ct[64][131];      // col j holds t = t0-1+j (clamped)
  __shared__ float m_s[64], rz_s[64];
  const int tid = threadIdx.x;
  const int b = blockIdx.z;
  const int c0 = blockIdx.y << 6;
  const int t0 = blockIdx.x << 7;
  {
    const int row0 = tid >> 7, jc = tid & 127;
    for (int rr = row0; rr < 64; rr += 2) {
      const float* src = corr + ((size_t)b * C_ + c0 + rr) * Ls;
      for (int j = jc; j < 130; j += 128) {
        int t = t0 - 1 + j;
        t = max(0, min(t, Ls - 1));
        ct[rr][j] = src[t];
      }
    }
  }
  if (tid < 64) {
    float2 v = mZ[b * C_ + c0 + tid];
    m_s[tid] = v.x; rz_s[tid] = v.y;
  }
  __syncthreads();
  const float th = thresh[b];
  const int cl = tid & 63, ts = tid >> 6;
  for (int ii = 0; ii < 32; ++ii) {
    int tl = ts + (ii << 2);
    int tg = t0 + tl;
    float vm = ct[cl][tl], vc = ct[cl][tl + 1], vp = ct[cl][tl + 2];
    bool pk = (tg >= 1) && (tg <= Ls - 2) && (vc > vm) && (vc > vp) && (vc >= th);
    float a = pk ? vc : 0.f;
    float w = __expf(a - m_s[cl]) * rz_s[cl];
    size_t vb = ((size_t)b * L_ + (size_t)tg * s) * C_ + c0 + cl;
    float vv;
    if (s == 2) vv = (V[vb] + V[vb + C_]) * 0.5f;
    else vv = ((V[vb] + V[vb + C_]) + (V[vb + 2 * C_] + V[vb + 3 * C_])) * 0.25f;
    o[((size_t)b * Ls + tg) * C_ + c0 + cl] = w * vv;
  }
}

// ---------------------------------------------------------------------------
// K5b-final (s=1): out = sw0*w*v + sw1*lerp(o2) + sw2*lerp(o4). 128-tau tiles.
// ---------------------------------------------------------------------------
__launch_bounds__(256, 4)
__global__ void k_apply_final(const float* __restrict__ corr, const float* __restrict__ V,
                              const float2* __restrict__ mZ, const float* thresh,
                              const float* __restrict__ o2, const float* __restrict__ o4,
                              const float* __restrict__ sw, float* __restrict__ out) {
  __shared__ float ct[64][131];
  __shared__ float m_s[64], rz_s[64];
  const int Ls = 1024;
  const int tid = threadIdx.x;
  const int b = blockIdx.z;
  const int c0 = blockIdx.y << 6;
  const int t0 = blockIdx.x << 7;
  {
    const int row0 = tid >> 7, jc = tid & 127;
    for (int rr = row0; rr < 64; rr += 2) {
      const float* src = corr + ((size_t)b * C_ + c0 + rr) * Ls;
      for (int j = jc; j < 130; j += 128) {
        int t = t0 - 1 + j;
        t = max(0, min(t, Ls - 1));
        ct[rr][j] = src[t];
      }
    }
  }
  if (tid < 64) {
    float2 v = mZ[b * C_ + c0 + tid];
    m_s[tid] = v.x; rz_s[tid] = v.y;
  }
  __syncthreads();
  const float th = thresh[b];
  const float sw0 = sw[0], sw1 = sw[1], sw2 = sw[2];
  const int cl = tid & 63, ts = tid >> 6;
  for (int ii = 0; ii < 32; ++ii) {
    int tl = ts + (ii << 2);
    int tg = t0 + tl;
    float vm = ct[cl][tl], vc = ct[cl][tl + 1], vp = ct[cl][tl + 2];
    bool pk = (tg >= 1) && (tg <= Ls - 2) && (vc > vm) && (vc > vp) && (vc >= th);
    float a = pk ? vc : 0.f;
    float w = __expf(a - m_s[cl]) * rz_s[cl];
    float v1 = V[((size_t)b * L_ + tg) * C_ + c0 + cl];
    float r = sw0 * w * v1;
    {
      float srcp = fmaxf((tg + 0.5f) * 0.5f - 0.5f, 0.f);
      int x0 = (int)srcp;
      float lam = srcp - (float)x0;
      int x1 = min(x0 + 1, 511);
      const float* p = o2 + (size_t)b * 512 * C_ + c0 + cl;
      r += sw1 * ((1.f - lam) * p[(size_t)x0 * C_] + lam * p[(size_t)x1 * C_]);
    }
    {
      float srcp = fmaxf((tg + 0.5f) * 0.25f - 0.5f, 0.f);
      int x0 = (int)srcp;
      float lam = srcp - (float)x0;
      int x1 = min(x0 + 1, 255);
      const float* p = o4 + (size_t)b * 256 * C_ + c0 + cl;
      r += sw2 * ((1.f - lam) * p[(size_t)x0 * C_] + lam * p[(size_t)x1 * C_]);
    }
    out[((size_t)b * L_ + tg) * C_ + c0 + cl] = r;
  }
}

// ---------------------------------------------------------------------------
extern "C" void kernel_launch(void* const* d_in, const int* in_sizes, int n_in,
                              void* d_out, int out_size, void* d_ws, size_t ws_size,
                              hipStream_t stream) {
  const float* Q  = (const float*)d_in[0];
  const float* Kk = (const float*)d_in[1];
  const float* V  = (const float*)d_in[2];
  const float* sw = (const float*)d_in[3];
  const float* w1 = (const float*)d_in[4];
  const float* b1 = (const float*)d_in[5];
  const float* w2 = (const float*)d_in[6];
  const float* b2 = (const float*)d_in[7];
  const float* w3 = (const float*)d_in[8];
  const float* b3 = (const float*)d_in[9];
  float* out = (float*)d_out;

  char* ws = (char*)d_ws;
  size_t p = 0;
  auto alloc = [&](size_t n) { char* r = ws + p; p = (p + n + 255) & ~(size_t)255; return r; };
  // corr for all 3 scales: [s1 | s2 | s4], elem offsets 0 / 8388608 / 12582912
  float*  corr = (float*)alloc((size_t)(8388608 + 4194304 + 2097152) * 4);  // 58.7 MB
  // o-region: o2 (16.8MB) + o4 (8.4MB); pk_buf (22.5MB) aliases it (pk dies
  // after k_sel level 3; o2/o4 born at k_apply, strictly later in-stream).
  char*   oreg = alloc((size_t)25165824);
  float*  o2   = (float*)oreg;
  float*  o4   = (float*)(oreg + 16777216);
  u32*    pk   = (u32*)oreg;
  float*  cm       = (float*)alloc(3 * 16 * 1024 * 4);
  float2* mZ       = (float2*)alloc(3 * 16 * 512 * 8);
  double* s1d      = (double*)alloc(48 * 8);
  double* s2d      = (double*)alloc(48 * 8);
  u32*    histA    = (u32*)alloc(3 * 16 * 256 * 4);
  u32*    histB    = (u32*)alloc(3 * 16 * 256 * 4);
  u32*    peak_cnt = (u32*)alloc(3 * 16 * 16 * 4);   // padded: 1 counter / 64B
  u32*    done     = (u32*)alloc(144 * 4);
  int*    rank_s   = (int*)alloc(48 * 4);
  u32*    prefix_s = (u32*)alloc(48 * 4);
  u32*    active   = (u32*)alloc(48 * 4);
  float*  thresh   = (float*)alloc(48 * 4);

  k_init<<<dim3(16), dim3(256), 0, stream>>>(histA, histB, peak_cnt, done,
                                             s1d, s2d, cm);
  k_corr1<<<dim3(128, 8), dim3(512), 0, stream>>>(Q, Kk, corr);
  k_corr<2><<<dim3(128, 4), dim3(256), 0, stream>>>(Q, Kk, corr + 8388608);
  k_corr<4><<<dim3(128, 2), dim3(256), 0, stream>>>(Q, Kk, corr + 12582912);
  k_stats<<<dim3(C_ / GCH, B_, 3), dim3(256), 0, stream>>>(
      corr, cm, s1d, s2d, peak_cnt, histA, pk);
  k_mlp<<<dim3(48), dim3(256), 0, stream>>>(
      cm, s1d, s2d, peak_cnt, histA, rank_s, prefix_s, active, thresh,
      w1, b1, w2, b2, w3, b3);
  for (int level = 1; level <= 3; ++level)
    k_sel<<<dim3(48 * NB_SEL), dim3(256), 0, stream>>>(
        pk, peak_cnt, active, rank_s, prefix_s, histB, done, thresh, level);
  k_softstats<<<dim3(8192, 3), dim3(256), 0, stream>>>(corr, thresh, mZ);
  k_apply<<<dim3(2, 8, 16), dim3(256), 0, stream>>>(
      corr + 12582912, V, mZ + 2 * 8192, thresh + 32, o4, 256, 4);
  k_apply<<<dim3(4, 8, 16), dim3(256), 0, stream>>>(
      corr + 8388608, V, mZ + 1 * 8192, thresh + 16, o2, 512, 2);
  k_apply_final<<<dim3(8, 8, 16), dim3(256), 0, stream>>>(
      corr, V, mZ, thresh, o2, o4, sw, out);
}

// Round 7
// 800.672 us; speedup vs baseline: 1.1590x; 1.0092x over previous
//
#include <hip/hip_runtime.h>
#include <math.h>

typedef unsigned int u32;
typedef unsigned long long u64;
typedef float f4 __attribute__((ext_vector_type(4)));

#define B_ 16
#define L_ 1024
#define H_ 8
#define E_ 64
#define C_ 512            // H_*E_
#define NB_SEL 8          // blocks per (scale,b) in k_sel
#define GCH 8             // channels per k_stats block
#define TC 32             // k_corr time-chunk
#define CAPR 160          // k_corr<S> circular K-buffer rows (= 127 + TC + 1)
#define CAP1 192          // k_corr1 ring rows (mod-192)
#define KGRP 56           // K groups: 48 ring + 8 dup (rows 0..31 @ 192..223)

// scale indexing: sidx 0 -> s=1 (Ls=1024), 1 -> s=2 (512), 2 -> s=4 (256)
__device__ __forceinline__ size_t co(int sidx) {       // corr elem offset
  return sidx == 0 ? 0u : (sidx == 1 ? 8388608u : 12582912u);
}
__device__ __forceinline__ u32 pk_off(int sidx) {      // pk elem offset in o-region
  return sidx == 0 ? 0u : (sidx == 1 ? 3211264u : 4816896u);
}
__device__ __forceinline__ u32 pk_cap(int sidx) { return 200704u >> sidx; }

__device__ __forceinline__ u32 f2key(float f) {
  u32 u = __float_as_uint(f);
  return (u & 0x80000000u) ? ~u : (u | 0x80000000u);
}
__device__ __forceinline__ float key2f(u32 k) {
  u32 u = (k & 0x80000000u) ? (k ^ 0x80000000u) : ~k;
  return __uint_as_float(u);
}

// ---------------------------------------------------------------------------
// K_init: zero control state once (single-pass pipeline -> no mid-run resets)
// ---------------------------------------------------------------------------
__global__ void k_init(u32* histA, u32* histB, u32* peak_cnt, u32* done,
                       double* s1, double* s2, float* cm) {
  const int gid = blockIdx.x * 256 + threadIdx.x;
  const int gs = gridDim.x * 256;
  for (int i = gid; i < 3 * 16 * 256; i += gs) { histA[i] = 0; histB[i] = 0; }
  for (int i = gid; i < 3 * 16 * 1024; i += gs) cm[i] = 0.f;
  for (int i = gid; i < 3 * 16 * 16; i += gs) peak_cnt[i] = 0;
  for (int i = gid; i < 144; i += gs) done[i] = 0;
  for (int i = gid; i < 48; i += gs) { s1[i] = 0.0; s2[i] = 0.0; }
}

// ---------------------------------------------------------------------------
// K1-S1: circular cross-correlation, fp32 direct, register-tiled.
// r6 structure (512 thr / 8 waves / 16 tau per wave, reg-staged, one barrier
// per chunk) with the LDS geometry fixed: 4-row-interleaved groups
//   addr(p,e) = (p>>2)*256 + e*4 + (p&3)
// so every b128 access has lanes striding 16B (native conflict-free pattern;
// r6's [e][p] rows strode 1KB == 0 mod 128B -> 8-way conflicts, 2.1e7 cyc).
//  - km: 12 ds_read_b128 (f4 = rows 4G..4G+3 -> km4[m>>2][m&3], FMA loop
//    identical to r6). q: 8 b128 from [t/4][e][4] double buffer.
//  - ring 192 rows (48 groups) + 8 dup groups (rows 0..31 imaged @192..223;
//    max window row = 176+46 = 222). Reads [cph,cph+159] / writes
//    [cph+160,cph+191] stay disjoint -> ONE barrier per chunk.
//  - LDS 56KB + 16KB = 72KB -> 2 blocks/CU = 4 waves/SIMD (as r2/r6).
//  - launch_bounds(512,4): r6 compiled this register content to 64 VGPR.
// ---------------------------------------------------------------------------
__launch_bounds__(512, 4)
__global__ void k_corr1(const float* __restrict__ Q, const float* __restrict__ K,
                        float* __restrict__ corr) {
  constexpr int LS = 1024;
  constexpr int LMASK = LS - 1;
  constexpr int NCHUNK = LS / TC;     // 32
  __shared__ __align__(16) float ksT[KGRP * 256];   // 56KB [p/4][e][4]
  __shared__ __align__(16) float qT[2 * 8 * 256];   // 16KB [buf][t/4][e][4]
  const int tid = threadIdx.x;        // 0..511
  const int e = tid & 63;
  const int w = tid >> 6;             // wave 0..7
  const int slot16 = __builtin_amdgcn_readfirstlane(w << 4);
  const int bh = blockIdx.x;
  const int tau0 = blockIdx.y << 7;         // *128
  const int b = bh >> 3, h = bh & 7;
  const size_t gbase = (size_t)b * L_ * C_ + (size_t)h * 64;
  const int e4 = e << 2;                    // lane's float offset inside group
  const int bp0 = 112 - slot16;             // wave-uniform, in {0,16,...,112}

  float acc[16];
#pragma unroll
  for (int i = 0; i < 16; ++i) acc[i] = 0.f;

  // prologue: K logical rows 0..159 (5 passes of 32 rows; wave w stages rows
  // pass*32+4w..+3); q rows 0..31 into buf0 (wave w -> group w).
#pragma unroll
  for (int pass = 0; pass < 5; ++pass) {
    const int p0 = pass * 32 + (w << 2);
    f4 v;
#pragma unroll
    for (int j = 0; j < 4; ++j) {
      int tk = (p0 + j - tau0 - 127 + 2048) & LMASK;
      v[j] = K[gbase + (size_t)tk * C_ + e];
    }
    *(f4*)&ksT[(p0 >> 2) * 256 + e4] = v;
    if (p0 < 32) *(f4*)&ksT[((p0 + 192) >> 2) * 256 + e4] = v;  // dup image
  }
  {
    f4 v;
#pragma unroll
    for (int j = 0; j < 4; ++j)
      v[j] = Q[gbase + (size_t)((w << 2) + j) * C_ + e];
    *(f4*)&qT[w * 256 + e4] = v;
  }
  __syncthreads();

  int cph = 0;                              // (chunk*32) mod 192
  for (int chunk = 0; chunk < NCHUNK; ++chunk) {
    const int t0 = chunk * TC;
    const bool more = (chunk + 1 < NCHUNK);
    // ---- issue global loads for chunk+1 (latency hides under compute) ----
    f4 kr, qr;
    int sr = 0;
    if (more) {
      int sp = cph + 160; if (sp >= CAP1) sp -= CAP1;  // 32-aligned
      sr = sp + (w << 2);                              // <= 188, no wrap
#pragma unroll
      for (int j = 0; j < 4; ++j) {
        int l = t0 + 160 + (w << 2) + j;
        int tk = (l - tau0 - 127 + 2048) & LMASK;
        kr[j] = K[gbase + (size_t)tk * C_ + e];
      }
#pragma unroll
      for (int j = 0; j < 4; ++j)
        qr[j] = Q[gbase + (size_t)(t0 + TC + (w << 2) + j) * C_ + e];
    }
    // ---- compute: 16 taus x 32 jt over a 47-row k-window, all b128 -------
    int bp = bp0 + cph; if (bp >= CAP1) bp -= CAP1;    // wave-uniform, 16-aligned
    const int g0 = bp >> 2;                            // group base (<= 44)
    f4 km4[12];                                        // rows bp..bp+47
#pragma unroll
    for (int j = 0; j < 12; ++j)
      km4[j] = *(const f4*)&ksT[(g0 + j) * 256 + e4];  // dup covers >= group 48
    const float* qb = qT + (chunk & 1) * 2048;
#pragma unroll
    for (int g = 0; g < 8; ++g) {
      f4 qv = *(const f4*)&qb[g * 256 + e4];
#pragma unroll
      for (int k = 0; k < 4; ++k) {
        const int jt = (g << 2) + k;
#pragma unroll
        for (int i = 0; i < 16; ++i) {
          const int m = 15 + jt - i;                   // 0..46, compile-time
          acc[i] = fmaf(qv[k], km4[m >> 2][m & 3], acc[i]);
        }
      }
    }
    // ---- write staged data (logical rows disjoint from read window) ------
    if (more) {
      *(f4*)&ksT[(sr >> 2) * 256 + e4] = kr;
      if (sr < 32) *(f4*)&ksT[((sr + 192) >> 2) * 256 + e4] = kr;
      float* qn = qT + (((chunk & 1) ^ 1)) * 2048;
      *(f4*)&qn[w * 256 + e4] = qr;
    }
    __syncthreads();    // staged writes visible before next chunk's reads
    cph += 32; if (cph >= CAP1) cph -= CAP1;
  }
  // transpose in LDS, coalesced write (tau-contiguous rows) ----------------
  float* wt = ksT;  // 128*65 = 8320 floats <= 14336
#pragma unroll
  for (int i = 0; i < 16; ++i) wt[(slot16 + i) * 65 + e] = acc[i];
  __syncthreads();
  const int to = tid & 127;
  const size_t cbase = ((size_t)b * C_ + (size_t)h * 64) * LS + tau0 + to;
  for (int cr = tid >> 7; cr < 64; cr += 4)
    corr[cbase + (size_t)cr * LS] = wt[to * 65 + cr];
}

// ---------------------------------------------------------------------------
// K1 (S=2,4): pooled correlation, fp32 direct, register-tiled, circular-K.
// ---------------------------------------------------------------------------
template<int S>
__device__ __forceinline__ float4 pool_load(const float* gp) {
  float4 v = *(const float4*)gp;
  if constexpr (S >= 2) {
    float4 v2 = *(const float4*)(gp + C_);
    v.x += v2.x; v.y += v2.y; v.z += v2.z; v.w += v2.w;
  }
  if constexpr (S == 4) {
    float4 v3 = *(const float4*)(gp + 2 * C_);
    float4 v4 = *(const float4*)(gp + 3 * C_);
    v.x += v3.x + v4.x; v.y += v3.y + v4.y;
    v.z += v3.z + v4.z; v.w += v3.w + v4.w;
  }
  constexpr float sc = (S == 1) ? 1.f : (S == 2) ? 0.5f : 0.25f;
  if constexpr (S >= 2) { v.x *= sc; v.y *= sc; v.z *= sc; v.w *= sc; }
  return v;
}

template<int S>
__launch_bounds__(256, 3)
__global__ void k_corr(const float* __restrict__ Q, const float* __restrict__ K,
                       float* __restrict__ corr) {
  constexpr int LS = 1024 / S;
  constexpr int LMASK = LS - 1;
  constexpr int NCHUNK = LS / TC;
  __shared__ float qs[TC * 64];       // 8KB  [t_local][e]
  __shared__ float ks[CAPR * 64];     // 40KB circular [p][e]; reused for transpose
  const int tid = threadIdx.x;
  const int e = tid & 63;
  const int slot32 = __builtin_amdgcn_readfirstlane((tid >> 6) << 5);
  const int bh = blockIdx.x;
  const int tau0 = blockIdx.y << 7;         // *128
  const int b = bh >> 3, h = bh & 7;
  const size_t gbase = (size_t)b * L_ * C_ + (size_t)h * 64;
  const int l16 = tid & 15;                 // float4 lane within a 64-e row
  const int rbase = tid >> 4;               // 16 rows per staging iteration
  const int bp0 = 96 - slot32;              // wave-uniform, in {0,32,64,96}

  float acc[32];
#pragma unroll
  for (int i = 0; i < 32; ++i) acc[i] = 0.f;

  int cph = 0;                              // (chunk*32) mod 160
  for (int chunk = 0; chunk < NCHUNK; ++chunk) {
    const int t0 = chunk * TC;
    __syncthreads();                        // prev chunk's LDS reads done
    {
      // stage q: 32 rows
#pragma unroll
      for (int it = 0; it < 2; ++it) {
        int row = rbase + it * 16;
        int traw = (t0 + row) * S;
        float4 v = pool_load<S>(Q + gbase + (size_t)traw * C_ + l16 * 4);
        *(float4*)(qs + row * 64 + l16 * 4) = v;
      }
      if (chunk == 0) {
#pragma unroll
        for (int it = 0; it < 10; ++it) {
          int l = rbase + it * 16;
          int tk = (l - tau0 - 127 + 2048) & LMASK;
          float4 v = pool_load<S>(K + gbase + (size_t)tk * S * C_ + l16 * 4);
          *(float4*)(ks + l * 64 + l16 * 4) = v;
        }
      } else {
        int sp = cph + 128; if (sp >= CAPR) sp -= CAPR;
#pragma unroll
        for (int it = 0; it < 2; ++it) {
          int row = rbase + it * 16;
          int l = t0 + 128 + row;
          int tk = (l - tau0 - 127 + 2048) & LMASK;
          int p = sp + row; if (p >= CAPR) p -= CAPR;
          float4 v = pool_load<S>(K + gbase + (size_t)tk * S * C_ + l16 * 4);
          *(float4*)(ks + p * 64 + l16 * 4) = v;
        }
      }
      __syncthreads();
    }
    // ---- compute: two 16x32 register tiles over a 63-reg k-window
    int bp = bp0 + cph; if (bp >= CAPR) bp -= CAPR;   // wave-uniform
    float km[63];
    if (bp <= CAPR - 47) {
#pragma unroll
      for (int m = 0; m < 47; ++m) km[m] = ks[(bp + m) * 64 + e];
    } else {
#pragma unroll
      for (int m = 0; m < 47; ++m) {
        int p = bp + m; if (p >= CAPR) p -= CAPR;
        km[m] = ks[p * 64 + e];
      }
    }
#pragma unroll
    for (int jt = 0; jt < 16; ++jt) {
      float qv = qs[jt * 64 + e];
#pragma unroll
      for (int i = 0; i < 32; ++i) acc[i] = fmaf(qv, km[31 + jt - i], acc[i]);
    }
    if (bp <= CAPR - 63) {
#pragma unroll
      for (int m = 47; m < 63; ++m) km[m] = ks[(bp + m) * 64 + e];
    } else {
#pragma unroll
      for (int m = 47; m < 63; ++m) {
        int p = bp + m; if (p >= CAPR) p -= CAPR;
        km[m] = ks[p * 64 + e];
      }
    }
#pragma unroll
    for (int jt = 16; jt < 32; ++jt) {
      float qv = qs[jt * 64 + e];
#pragma unroll
      for (int i = 0; i < 32; ++i) acc[i] = fmaf(qv, km[31 + jt - i], acc[i]);
    }
    cph += 32; if (cph >= CAPR) cph -= CAPR;
  }
  // transpose in LDS, coalesced write (tau-contiguous rows) ----------------
  __syncthreads();
  float* wt = ks;  // 128*65 = 8320 floats <= 10240
#pragma unroll
  for (int i = 0; i < 32; ++i) wt[(slot32 + i) * 65 + e] = acc[i];
  __syncthreads();
  const int to = tid & 127;
  const size_t cbase = ((size_t)b * C_ + (size_t)h * 64) * LS + tau0 + to;
  for (int cr = tid >> 7; cr < 64; cr += 2)
    corr[cbase + (size_t)cr * LS] = wt[to * 65 + cr];
}

// ---------------------------------------------------------------------------
// K2 (merged scales): per-(scale,b) stats, cm partials, peak detect +
// compaction (one global atomic per block) + level-0 histogram.
// Grid: (C_/GCH, B, 3).
// ---------------------------------------------------------------------------
__launch_bounds__(256, 4)
__global__ void k_stats(const float* __restrict__ corrbase, float* __restrict__ cm,
                        double* s1, double* s2, u32* peak_cnt, u32* histA,
                        u32* pkbase) {
  __shared__ __align__(16) float rows[GCH * 1024];
  __shared__ u32 hist_s[256];
  __shared__ double red_d[8];
  __shared__ u32 wv[4], wbase[4];
  const int tid = threadIdx.x;
  const int sidx = blockIdx.z;
  const int b = blockIdx.y;
  const int sb = sidx * 16 + b;
  const int Ls = 1024 >> sidx;
  const int c0 = blockIdx.x * GCH;
  const int lane = tid & 63;
  const int wave = tid >> 6;
  hist_s[tid] = 0;
  {
    const float4* src4 =
        (const float4*)(corrbase + co(sidx) + ((size_t)b * C_ + c0) * Ls);
    float4* dst4 = (float4*)rows;
    const int n4 = GCH * Ls / 4;
    for (int i = tid; i < n4; i += 256) dst4[i] = src4[i];
  }
  __syncthreads();
  const int nt = Ls >> 8;         // taus per thread: 4/2/1
  float cmacc[4] = {0.f, 0.f, 0.f, 0.f};
  double ls1 = 0.0, ls2 = 0.0;
  u32 mycnt = 0;
  // ---- phase 1: stats + peak count + level-0 hist
  for (int g = 0; g < GCH; ++g) {
    const float* row = rows + g * Ls;
    for (int i = 0; i < nt; ++i) {
      int t = tid + (i << 8);
      float v = row[t];
      cmacc[i] += v;
      ls1 += (double)v;
      ls2 += (double)v * (double)v;
      bool pk = (t >= 1) && (t <= Ls - 2) && (v > row[t - 1]) && (v > row[t + 1]);
      if (pk) {
        ++mycnt;
        atomicAdd(&hist_s[f2key(v) >> 24], 1u);
      }
    }
  }
  // block-scan peak counts -> single global atomic for base
  u32 wc = mycnt;
  for (int off = 32; off; off >>= 1) wc += __shfl_down(wc, off, 64);
  if (lane == 0) wv[wave] = wc;
  __syncthreads();
  if (tid == 0) {
    u32 t = 0;
    for (int w = 0; w < 4; ++w) { wbase[w] = t; t += wv[w]; }
    u32 base = atomicAdd(&peak_cnt[sb * 16], t);
    for (int w = 0; w < 4; ++w) wbase[w] += base;
  }
  __syncthreads();
  // ---- phase 2: re-detect, compacted write at deterministic offsets
  const u32 cap = pk_cap(sidx);
  u32* dst_pk = pkbase + pk_off(sidx) + (u32)b * cap;
  u32 off_w = wbase[wave];
  const u64 below = (1ull << lane) - 1ull;
  for (int g = 0; g < GCH; ++g) {
    const float* row = rows + g * Ls;
    for (int i = 0; i < nt; ++i) {
      int t = tid + (i << 8);
      float v = row[t];
      bool pk = (t >= 1) && (t <= Ls - 2) && (v > row[t - 1]) && (v > row[t + 1]);
      u64 mask = __ballot(pk);
      if (pk) {
        u32 idx = off_w + (u32)__popcll(mask & below);
        if (idx < cap) dst_pk[idx] = f2key(v);
      }
      off_w += (u32)__popcll(mask);
    }
  }
  // cm partials: one unsafe float atomic per owned tau
  for (int i = 0; i < nt; ++i) {
    int t = tid + (i << 8);
    unsafeAtomicAdd(&cm[sb * 1024 + t], cmacc[i]);
  }
  // s1/s2: wave reduce -> block reduce -> one double atomic per block
  for (int off = 32; off; off >>= 1) {
    ls1 += __shfl_down(ls1, off, 64);
    ls2 += __shfl_down(ls2, off, 64);
  }
  if (lane == 0) { red_d[wave] = ls1; red_d[4 + wave] = ls2; }
  __syncthreads();
  if (tid == 0) {
    unsafeAtomicAdd(&s1[sb], red_d[0] + red_d[1] + red_d[2] + red_d[3]);
    unsafeAtomicAdd(&s2[sb], red_d[4] + red_d[5] + red_d[6] + red_d[7]);
  }
  if (hist_s[tid]) atomicAdd(&histA[sb * 256 + tid], hist_s[tid]);
}

// ---------------------------------------------------------------------------
// K3 (merged): one block per (scale,b). cm pk-count, MLP -> kvals, level-0
// radix scan (snapshot-then-write). Energy computed redundantly per block.
// ---------------------------------------------------------------------------
__global__ void k_mlp(const float* __restrict__ cm, const double* s1,
                      const double* s2, const u32* peak_cnt, const u32* histA,
                      int* rank_s, u32* prefix_s, u32* active, float* thresh,
                      const float* w1, const float* b1, const float* w2,
                      const float* b2, const float* w3, const float* b3) {
  __shared__ float wls[673];       // w1(96) b1(32) w2(512) b2(16) w3(16) b3(1)
  __shared__ float cmrow[1024];
  __shared__ int red_i[4];
  __shared__ u32 cum[256];
  const int tid = threadIdx.x;
  const int sb = blockIdx.x;
  const int sidx = sb >> 4;
  const int Ls = 1024 >> sidx;
  for (int i = tid; i < 96; i += 256) wls[i] = w1[i];
  for (int i = tid; i < 32; i += 256) wls[96 + i] = b1[i];
  for (int i = tid; i < 512; i += 256) wls[128 + i] = w2[i];
  if (tid < 16) wls[640 + tid] = b2[tid];
  if (tid < 16) wls[656 + tid] = w3[tid];
  if (tid == 0) wls[672] = b3[0];
  for (int i = tid; i < Ls; i += 256) cmrow[i] = cm[sb * 1024 + i];
  __syncthreads();
  int cnt = 0;
  for (int t = 1 + tid; t <= Ls - 2; t += 256) {
    float v = cmrow[t];
    cnt += (v > cmrow[t - 1]) && (v > cmrow[t + 1]);
  }
  for (int off = 32; off; off >>= 1) cnt += __shfl_down(cnt, off, 64);
  if ((tid & 63) == 0) red_i[tid >> 6] = cnt;
  __syncthreads();
  if (tid == 0) {
    double tot = 0.0;
    for (int j = 0; j < 16; ++j) tot += s2[sidx * 16 + j];
    float f0 = (float)(tot / (16.0 * (double)Ls));
    double N = (double)C_ * (double)Ls;
    float f1 = (float)((s2[sb] - s1[sb] * s1[sb] / N) / (N - 1.0));
    float f2 = (float)(red_i[0] + red_i[1] + red_i[2] + red_i[3]);
    float h1[32];
    for (int j = 0; j < 32; ++j)
      h1[j] = fmaxf(0.f, wls[j * 3] * f0 + wls[j * 3 + 1] * f1 + wls[j * 3 + 2] * f2 + wls[96 + j]);
    float h2[16];
    for (int j = 0; j < 16; ++j) {
      float a = wls[640 + j];
      for (int i = 0; i < 32; ++i) a += wls[128 + j * 32 + i] * h1[i];
      h2[j] = fmaxf(0.f, a);
    }
    float z = wls[672];
    for (int i = 0; i < 16; ++i) z += wls[656 + i] * h2[i];
    float ratio = 1.0f / (1.0f + __expf(-z));
    int kv = (int)(ratio * (float)Ls);
    kv = min(max(kv, 1), Ls);
    int cntb = (int)peak_cnt[sb * 16];
    active[sb] = (u32)(cntb > kv);
    thresh[sb] = -INFINITY;
    rank_s[sb] = kv;
    prefix_s[sb] = 0;
  }
  __syncthreads();
  // level-0 radix scan: parallel suffix-scan over 256 bins
  cum[tid] = histA[sb * 256 + tid];
  __syncthreads();
  for (int off = 1; off < 256; off <<= 1) {
    u32 add = (tid + off < 256) ? cum[tid + off] : 0u;
    __syncthreads();
    cum[tid] += add;
    __syncthreads();
  }
  u32 act_b = active[sb];
  u32 r = act_b ? (u32)rank_s[sb] : 0u;
  u32 cc = cum[tid];
  u32 cnext = (tid == 255) ? 0u : cum[tid + 1];
  __syncthreads();          // all snapshots done before any write
  if (act_b && r > 0 && cc >= r && cnext < r) {
    prefix_s[sb] = (u32)tid << 24;
    rank_s[sb] = (int)(r - cnext);
  }
}

// ---------------------------------------------------------------------------
// K_sel (levels 1..3): full key scan, LDS->global hist, ticket finisher does
// the parallel suffix-scan + snapshot-write refine. Grid: 3*16*NB_SEL.
// ---------------------------------------------------------------------------
__global__ void k_sel(const u32* __restrict__ pkbase, const u32* peak_cnt,
                      const u32* active, int* rank_s, u32* prefix_s,
                      u32* hist, u32* done, float* thresh, int level) {
  __shared__ u32 hist_s[256];
  __shared__ u32 cum[256];
  __shared__ u32 islast;
  const int tid = threadIdx.x;
  const int sb = blockIdx.x / NB_SEL;
  const int blk = blockIdx.x % NB_SEL;
  const int sidx = sb >> 4;
  hist_s[tid] = 0;
  if (tid == 0) islast = 0;
  __syncthreads();
  const int act = (int)active[sb];
  const u32 cap = pk_cap(sidx);
  u32 cnt = peak_cnt[sb * 16];
  if (cnt > cap) cnt = cap;
  if (act) {
    const u32 pref = prefix_s[sb];
    const int hi_sh = 32 - 8 * level;
    const int b_sh = 24 - 8 * level;
    const u32 lo = (u32)(((u64)cnt * (u64)blk) / NB_SEL);
    const u32 hi = (u32)(((u64)cnt * (u64)(blk + 1)) / NB_SEL);
    const u32* src = pkbase + pk_off(sidx) + (u32)(sb & 15) * cap;
    for (u32 i = lo + tid; i < hi; i += 256) {
      u32 key = src[i];
      if ((key >> hi_sh) == (pref >> hi_sh))
        atomicAdd(&hist_s[(key >> b_sh) & 255u], 1u);
    }
  }
  __syncthreads();
  if (hist_s[tid]) atomicAdd(&hist[sb * 256 + tid], hist_s[tid]);
  __syncthreads();                        // barrier drains all vmem (vmcnt(0))
  if (tid == 0) {
    __threadfence();
    u32 t = atomicAdd(&done[(level - 1) * 48 + sb], 1u);
    if (t == NB_SEL - 1) islast = 1;
  }
  __syncthreads();
  if (!islast) return;
  // ---- finisher (exactly one block per (scale,b))
  __threadfence();
  u32 hv = atomicAdd(&hist[sb * 256 + tid], 0u);    // atomic read
  cum[tid] = hv;
  hist[sb * 256 + tid] = 0;               // ready for next level
  __syncthreads();
  for (int off = 1; off < 256; off <<= 1) {
    u32 add = (tid + off < 256) ? cum[tid + off] : 0u;
    __syncthreads();
    cum[tid] += add;
    __syncthreads();
  }
  u32 r = act ? (u32)rank_s[sb] : 0u;
  u32 pref2 = act ? prefix_s[sb] : 0u;
  u32 cc = cum[tid];
  u32 cnext = (tid == 255) ? 0u : cum[tid + 1];
  __syncthreads();                        // snapshots before write
  if (act && r > 0 && cc >= r && cnext < r) {
    u32 np = pref2 | ((u32)tid << (24 - 8 * level));
    prefix_s[sb] = np;
    rank_s[sb] = (int)(r - cnext);
    if (level == 3) thresh[sb] = key2f(np);
  }
}

// ---------------------------------------------------------------------------
// K5a (merged): per-(scale,b,c) softmax stats. Grid: (8192, 3).
// ---------------------------------------------------------------------------
__global__ void k_softstats(const float* __restrict__ corrbase, const float* thresh,
                            float2* __restrict__ mZ) {
  __shared__ float row[1024];
  __shared__ float red_s[8];
  const int tid = threadIdx.x;
  const int bc = blockIdx.x;
  const int sidx = blockIdx.y;
  const int Ls = 1024 >> sidx;
  const float th = thresh[sidx * 16 + (bc >> 9)];
  const float* src = corrbase + co(sidx) + (size_t)bc * Ls;
  for (int t = tid; t < Ls; t += 256) row[t] = src[t];
  __syncthreads();
  float mx = 0.f;   // zeros always present in attn row -> true max >= 0
  for (int t = tid; t < Ls; t += 256) {
    float v = row[t];
    bool pk = (t >= 1) && (t <= Ls - 2) && (v > row[t - 1]) && (v > row[t + 1]) && (v >= th);
    if (pk) mx = fmaxf(mx, v);
  }
  for (int off = 32; off; off >>= 1) mx = fmaxf(mx, __shfl_down(mx, off, 64));
  if ((tid & 63) == 0) red_s[tid >> 6] = mx;
  __syncthreads();
  float m = fmaxf(fmaxf(red_s[0], red_s[1]), fmaxf(red_s[2], red_s[3]));
  float zs = 0.f;
  for (int t = tid; t < Ls; t += 256) {
    float v = row[t];
    bool pk = (t >= 1) && (t <= Ls - 2) && (v > row[t - 1]) && (v > row[t + 1]) && (v >= th);
    float a = pk ? v : 0.f;
    zs += __expf(a - m);
  }
  for (int off = 32; off; off >>= 1) zs += __shfl_down(zs, off, 64);
  if ((tid & 63) == 0) red_s[4 + (tid >> 6)] = zs;
  __syncthreads();
  if (tid == 0) {
    float Z = red_s[4] + red_s[5] + red_s[6] + red_s[7];
    mZ[sidx * 8192 + bc] = make_float2(m, 1.0f / Z);
  }
}

// ---------------------------------------------------------------------------
// K5b (s=2,4): o_s[b][tau][c] = softmax-weight * pooled v. 128-tau tiles.
// corr/mZ/thresh passed pre-offset for the scale.
// ---------------------------------------------------------------------------
__launch_bounds__(256, 4)
__global__ void k_apply(const float* __restrict__ corr, const float* __restrict__ V,
                        const float2* __restrict__ mZ, const float* thresh,
                        float* __restrict__ o, int Ls, int s) {
  __shared__ float ct[64][131];      // col j holds t = t0-1+j (clamped)
  __shared__ float m_s[64], rz_s[64];
  const int tid = threadIdx.x;
  const int b = blockIdx.z;
  const int c0 = blockIdx.y << 6;
  const int t0 = blockIdx.x << 7;
  {
    const int row0 = tid >> 7, jc = tid & 127;
    for (int rr = row0; rr < 64; rr += 2) {
      const float* src = corr + ((size_t)b * C_ + c0 + rr) * Ls;
      for (int j = jc; j < 130; j += 128) {
        int t = t0 - 1 + j;
        t = max(0, min(t, Ls - 1));
        ct[rr][j] = src[t];
      }
    }
  }
  if (tid < 64) {
    float2 v = mZ[b * C_ + c0 + tid];
    m_s[tid] = v.x; rz_s[tid] = v.y;
  }
  __syncthreads();
  const float th = thresh[b];
  const int cl = tid & 63, ts = tid >> 6;
  for (int ii = 0; ii < 32; ++ii) {
    int tl = ts + (ii << 2);
    int tg = t0 + tl;
    float vm = ct[cl][tl], vc = ct[cl][tl + 1], vp = ct[cl][tl + 2];
    bool pk = (tg >= 1) && (tg <= Ls - 2) && (vc > vm) && (vc > vp) && (vc >= th);
    float a = pk ? vc : 0.f;
    float w = __expf(a - m_s[cl]) * rz_s[cl];
    size_t vb = ((size_t)b * L_ + (size_t)tg * s) * C_ + c0 + cl;
    float vv;
    if (s == 2) vv = (V[vb] + V[vb + C_]) * 0.5f;
    else vv = ((V[vb] + V[vb + C_]) + (V[vb + 2 * C_] + V[vb + 3 * C_])) * 0.25f;
    o[((size_t)b * Ls + tg) * C_ + c0 + cl] = w * vv;
  }
}

// ---------------------------------------------------------------------------
// K5b-final (s=1): out = sw0*w*v + sw1*lerp(o2) + sw2*lerp(o4). 128-tau tiles.
// ---------------------------------------------------------------------------
__launch_bounds__(256, 4)
__global__ void k_apply_final(const float* __restrict__ corr, const float* __restrict__ V,
                              const float2* __restrict__ mZ, const float* thresh,
                              const float* __restrict__ o2, const float* __restrict__ o4,
                              const float* __restrict__ sw, float* __restrict__ out) {
  __shared__ float ct[64][131];
  __shared__ float m_s[64], rz_s[64];
  const int Ls = 1024;
  const int tid = threadIdx.x;
  const int b = blockIdx.z;
  const int c0 = blockIdx.y << 6;
  const int t0 = blockIdx.x << 7;
  {
    const int row0 = tid >> 7, jc = tid & 127;
    for (int rr = row0; rr < 64; rr += 2) {
      const float* src = corr + ((size_t)b * C_ + c0 + rr) * Ls;
      for (int j = jc; j < 130; j += 128) {
        int t = t0 - 1 + j;
        t = max(0, min(t, Ls - 1));
        ct[rr][j] = src[t];
      }
    }
  }
  if (tid < 64) {
    float2 v = mZ[b * C_ + c0 + tid];
    m_s[tid] = v.x; rz_s[tid] = v.y;
  }
  __syncthreads();
  const float th = thresh[b];
  const float sw0 = sw[0], sw1 = sw[1], sw2 = sw[2];
  const int cl = tid & 63, ts = tid >> 6;
  for (int ii = 0; ii < 32; ++ii) {
    int tl = ts + (ii << 2);
    int tg = t0 + tl;
    float vm = ct[cl][tl], vc = ct[cl][tl + 1], vp = ct[cl][tl + 2];
    bool pk = (tg >= 1) && (tg <= Ls - 2) && (vc > vm) && (vc > vp) && (vc >= th);
    float a = pk ? vc : 0.f;
    float w = __expf(a - m_s[cl]) * rz_s[cl];
    float v1 = V[((size_t)b * L_ + tg) * C_ + c0 + cl];
    float r = sw0 * w * v1;
    {
      float srcp = fmaxf((tg + 0.5f) * 0.5f - 0.5f, 0.f);
      int x0 = (int)srcp;
      float lam = srcp - (float)x0;
      int x1 = min(x0 + 1, 511);
      const float* p = o2 + (size_t)b * 512 * C_ + c0 + cl;
      r += sw1 * ((1.f - lam) * p[(size_t)x0 * C_] + lam * p[(size_t)x1 * C_]);
    }
    {
      float srcp = fmaxf((tg + 0.5f) * 0.25f - 0.5f, 0.f);
      int x0 = (int)srcp;
      float lam = srcp - (float)x0;
      int x1 = min(x0 + 1, 255);
      const float* p = o4 + (size_t)b * 256 * C_ + c0 + cl;
      r += sw2 * ((1.f - lam) * p[(size_t)x0 * C_] + lam * p[(size_t)x1 * C_]);
    }
    out[((size_t)b * L_ + tg) * C_ + c0 + cl] = r;
  }
}

// ---------------------------------------------------------------------------
extern "C" void kernel_launch(void* const* d_in, const int* in_sizes, int n_in,
                              void* d_out, int out_size, void* d_ws, size_t ws_size,
                              hipStream_t stream) {
  const float* Q  = (const float*)d_in[0];
  const float* Kk = (const float*)d_in[1];
  const float* V  = (const float*)d_in[2];
  const float* sw = (const float*)d_in[3];
  const float* w1 = (const float*)d_in[4];
  const float* b1 = (const float*)d_in[5];
  const float* w2 = (const float*)d_in[6];
  const float* b2 = (const float*)d_in[7];
  const float* w3 = (const float*)d_in[8];
  const float* b3 = (const float*)d_in[9];
  float* out = (float*)d_out;

  char* ws = (char*)d_ws;
  size_t p = 0;
  auto alloc = [&](size_t n) { char* r = ws + p; p = (p + n + 255) & ~(size_t)255; return r; };
  // corr for all 3 scales: [s1 | s2 | s4], elem offsets 0 / 8388608 / 12582912
  float*  corr = (float*)alloc((size_t)(8388608 + 4194304 + 2097152) * 4);  // 58.7 MB
  // o-region: o2 (16.8MB) + o4 (8.4MB); pk_buf (22.5MB) aliases it (pk dies
  // after k_sel level 3; o2/o4 born at k_apply, strictly later in-stream).
  char*   oreg = alloc((size_t)25165824);
  float*  o2   = (float*)oreg;
  float*  o4   = (float*)(oreg + 16777216);
  u32*    pk   = (u32*)oreg;
  float*  cm       = (float*)alloc(3 * 16 * 1024 * 4);
  float2* mZ       = (float2*)alloc(3 * 16 * 512 * 8);
  double* s1d      = (double*)alloc(48 * 8);
  double* s2d      = (double*)alloc(48 * 8);
  u32*    histA    = (u32*)alloc(3 * 16 * 256 * 4);
  u32*    histB    = (u32*)alloc(3 * 16 * 256 * 4);
  u32*    peak_cnt = (u32*)alloc(3 * 16 * 16 * 4);   // padded: 1 counter / 64B
  u32*    done     = (u32*)alloc(144 * 4);
  int*    rank_s   = (int*)alloc(48 * 4);
  u32*    prefix_s = (u32*)alloc(48 * 4);
  u32*    active   = (u32*)alloc(48 * 4);
  float*  thresh   = (float*)alloc(48 * 4);

  k_init<<<dim3(16), dim3(256), 0, stream>>>(histA, histB, peak_cnt, done,
                                             s1d, s2d, cm);
  k_corr1<<<dim3(128, 8), dim3(512), 0, stream>>>(Q, Kk, corr);
  k_corr<2><<<dim3(128, 4), dim3(256), 0, stream>>>(Q, Kk, corr + 8388608);
  k_corr<4><<<dim3(128, 2), dim3(256), 0, stream>>>(Q, Kk, corr + 12582912);
  k_stats<<<dim3(C_ / GCH, B_, 3), dim3(256), 0, stream>>>(
      corr, cm, s1d, s2d, peak_cnt, histA, pk);
  k_mlp<<<dim3(48), dim3(256), 0, stream>>>(
      cm, s1d, s2d, peak_cnt, histA, rank_s, prefix_s, active, thresh,
      w1, b1, w2, b2, w3, b3);
  for (int level = 1; level <= 3; ++level)
    k_sel<<<dim3(48 * NB_SEL), dim3(256), 0, stream>>>(
        pk, peak_cnt, active, rank_s, prefix_s, histB, done, thresh, level);
  k_softstats<<<dim3(8192, 3), dim3(256), 0, stream>>>(corr, thresh, mZ);
  k_apply<<<dim3(2, 8, 16), dim3(256), 0, stream>>>(
      corr + 12582912, V, mZ + 2 * 8192, thresh + 32, o4, 256, 4);
  k_apply<<<dim3(4, 8, 16), dim3(256), 0, stream>>>(
      corr + 8388608, V, mZ + 1 * 8192, thresh + 16, o2, 512, 2);
  k_apply_final<<<dim3(8, 8, 16), dim3(256), 0, stream>>>(
      corr, V, mZ, thresh, o2, o4, sw, out);
}

// Round 8
// 764.190 us; speedup vs baseline: 1.2143x; 1.0477x over previous
//
#include <hip/hip_runtime.h>
#include <math.h>

typedef unsigned int u32;
typedef unsigned long long u64;
typedef float f4 __attribute__((ext_vector_type(4)));

#define B_ 16
#define L_ 1024
#define H_ 8
#define E_ 64
#define C_ 512            // H_*E_
#define NB_SEL 32         // blocks per (scale,b) in k_sel (was 8: 1.5 blk/CU)
#define GCH 8             // channels per k_stats block
#define TC 32             // k_corr time-chunk
#define CAP1 192          // k_corr ring rows (mod-192)
#define KGRP 56           // K groups: 48 ring + 8 dup (rows 0..31 @ 192..223)

// scale indexing: sidx 0 -> s=1 (Ls=1024), 1 -> s=2 (512), 2 -> s=4 (256)
__device__ __forceinline__ size_t co(int sidx) {       // corr elem offset
  return sidx == 0 ? 0u : (sidx == 1 ? 8388608u : 12582912u);
}
__device__ __forceinline__ u32 pk_off(int sidx) {      // pk elem offset in o-region
  return sidx == 0 ? 0u : (sidx == 1 ? 3211264u : 4816896u);
}
__device__ __forceinline__ u32 pk_cap(int sidx) { return 200704u >> sidx; }

__device__ __forceinline__ u32 f2key(float f) {
  u32 u = __float_as_uint(f);
  return (u & 0x80000000u) ? ~u : (u | 0x80000000u);
}
__device__ __forceinline__ float key2f(u32 k) {
  u32 u = (k & 0x80000000u) ? (k ^ 0x80000000u) : ~k;
  return __uint_as_float(u);
}

// ---------------------------------------------------------------------------
// K_init: zero control state once (single-pass pipeline -> no mid-run resets)
// ---------------------------------------------------------------------------
__global__ void k_init(u32* histA, u32* histB, u32* peak_cnt, u32* done,
                       double* s1, double* s2, float* cm) {
  const int gid = blockIdx.x * 256 + threadIdx.x;
  const int gs = gridDim.x * 256;
  for (int i = gid; i < 3 * 16 * 256; i += gs) { histA[i] = 0; histB[i] = 0; }
  for (int i = gid; i < 3 * 16 * 1024; i += gs) cm[i] = 0.f;
  for (int i = gid; i < 3 * 16 * 16; i += gs) peak_cnt[i] = 0;
  for (int i = gid; i < 144; i += gs) done[i] = 0;
  for (int i = gid; i < 48; i += gs) { s1[i] = 0.0; s2[i] = 0.0; }
}

// pooled gather: mean over S raw rows at pooled index tk, column e.
template<int S>
__device__ __forceinline__ float gpool(const float* base, int tk, int e) {
  float v = base[(size_t)(tk * S) * C_ + e];
  if constexpr (S >= 2) v += base[(size_t)(tk * S + 1) * C_ + e];
  if constexpr (S == 4) {
    v += base[(size_t)(tk * S + 2) * C_ + e];
    v += base[(size_t)(tk * S + 3) * C_ + e];
  }
  constexpr float sc = (S == 1) ? 1.f : (S == 2) ? 0.5f : 0.25f;
  if constexpr (S >= 2) v *= sc;
  return v;
}

// ---------------------------------------------------------------------------
// K1 (all scales): circular cross-correlation, fp32 direct, register-tiled.
// r7's verified structure, templated on S (S=1 instantiation == r7's kernel):
//  - 512 thr / 8 waves / 16 taus per wave; ring 192 rows mod-192; ONE barrier
//    per chunk (reads [cph,cph+158] disjoint from writes [cph+160,cph+191]).
//  - 4-row-interleaved LDS groups addr(p,e)=(p>>2)*256+e*4+(p&3): every b128
//    access strides 16B/lane -> 0 bank conflicts (verified r7).
//  - km: 12 ds_read_b128; q: 8 b128 from double buffer; FMA 512/thread/chunk.
//  - reg-staged with pooling folded into the 4xS gather loads (S=2,4 get the
//    r7 structure for the first time; was r0's b32/2-barrier design).
//  - LDS 56+16=72KB -> 2 blocks/CU = 4 waves/SIMD; VGPR 64 (r7 measured).
// ---------------------------------------------------------------------------
template<int S>
__launch_bounds__(512, 4)
__global__ void k_corr1(const float* __restrict__ Q, const float* __restrict__ K,
                        float* __restrict__ corr) {
  constexpr int LS = 1024 / S;
  constexpr int LMASK = LS - 1;
  constexpr int NCHUNK = LS / TC;     // 32 / 16 / 8
  __shared__ __align__(16) float ksT[KGRP * 256];   // 56KB [p/4][e][4]
  __shared__ __align__(16) float qT[2 * 8 * 256];   // 16KB [buf][t/4][e][4]
  const int tid = threadIdx.x;        // 0..511
  const int e = tid & 63;
  const int w = tid >> 6;             // wave 0..7
  const int slot16 = __builtin_amdgcn_readfirstlane(w << 4);
  const int bh = blockIdx.x;
  const int tau0 = blockIdx.y << 7;         // *128
  const int b = bh >> 3, h = bh & 7;
  const size_t gbase = (size_t)b * L_ * C_ + (size_t)h * 64;
  const float* Qb = Q + gbase;
  const float* Kb = K + gbase;
  const int e4 = e << 2;                    // lane's float offset inside group
  const int bp0 = 112 - slot16;             // wave-uniform, in {0,16,...,112}

  float acc[16];
#pragma unroll
  for (int i = 0; i < 16; ++i) acc[i] = 0.f;

  // prologue: K logical rows 0..159 (5 passes; wave w stages rows pass*32+4w..+3);
  // q rows 0..31 into buf0 (wave w -> group w). All pooled gathers.
#pragma unroll
  for (int pass = 0; pass < 5; ++pass) {
    const int p0 = pass * 32 + (w << 2);
    f4 v;
#pragma unroll
    for (int j = 0; j < 4; ++j) {
      int tk = (p0 + j - tau0 - 127 + 2048) & LMASK;
      v[j] = gpool<S>(Kb, tk, e);
    }
    *(f4*)&ksT[(p0 >> 2) * 256 + e4] = v;
    if (p0 < 32) *(f4*)&ksT[((p0 + 192) >> 2) * 256 + e4] = v;  // dup image
  }
  {
    f4 v;
#pragma unroll
    for (int j = 0; j < 4; ++j)
      v[j] = gpool<S>(Qb, (w << 2) + j, e);
    *(f4*)&qT[w * 256 + e4] = v;
  }
  __syncthreads();

  int cph = 0;                              // (chunk*32) mod 192
  for (int chunk = 0; chunk < NCHUNK; ++chunk) {
    const int t0 = chunk * TC;
    const bool more = (chunk + 1 < NCHUNK);
    // ---- issue global loads for chunk+1 (latency hides under compute) ----
    f4 kr, qr;
    int sr = 0;
    if (more) {
      int sp = cph + 160; if (sp >= CAP1) sp -= CAP1;  // 32-aligned
      sr = sp + (w << 2);                              // <= 188, no wrap
#pragma unroll
      for (int j = 0; j < 4; ++j) {
        int l = t0 + 160 + (w << 2) + j;
        int tk = (l - tau0 - 127 + 2048) & LMASK;
        kr[j] = gpool<S>(Kb, tk, e);
      }
#pragma unroll
      for (int j = 0; j < 4; ++j)
        qr[j] = gpool<S>(Qb, (t0 + TC + (w << 2) + j) & LMASK, e);
    }
    // ---- compute: 16 taus x 32 jt over a 47-row k-window, all b128 -------
    int bp = bp0 + cph; if (bp >= CAP1) bp -= CAP1;    // wave-uniform; <=176
    const int g0 = bp >> 2;                            // group base (<= 44)
    f4 km4[12];                                        // rows bp..bp+47
#pragma unroll
    for (int j = 0; j < 12; ++j)
      km4[j] = *(const f4*)&ksT[(g0 + j) * 256 + e4];  // dup covers >= group 48
    const float* qb = qT + (chunk & 1) * 2048;
#pragma unroll
    for (int g = 0; g < 8; ++g) {
      f4 qv = *(const f4*)&qb[g * 256 + e4];
#pragma unroll
      for (int k = 0; k < 4; ++k) {
        const int jt = (g << 2) + k;
#pragma unroll
        for (int i = 0; i < 16; ++i) {
          const int m = 15 + jt - i;                   // 0..46, compile-time
          acc[i] = fmaf(qv[k], km4[m >> 2][m & 3], acc[i]);
        }
      }
    }
    // ---- write staged data (logical rows disjoint from read window) ------
    if (more) {
      *(f4*)&ksT[(sr >> 2) * 256 + e4] = kr;
      if (sr < 32) *(f4*)&ksT[((sr + 192) >> 2) * 256 + e4] = kr;
      float* qn = qT + (((chunk & 1) ^ 1)) * 2048;
      *(f4*)&qn[w * 256 + e4] = qr;
    }
    __syncthreads();    // staged writes visible before next chunk's reads
    cph += 32; if (cph >= CAP1) cph -= CAP1;
  }
  // transpose in LDS, coalesced write (tau-contiguous rows) ----------------
  float* wt = ksT;  // 128*65 = 8320 floats <= 14336
#pragma unroll
  for (int i = 0; i < 16; ++i) wt[(slot16 + i) * 65 + e] = acc[i];
  __syncthreads();
  const int to = tid & 127;
  const size_t cbase = ((size_t)b * C_ + (size_t)h * 64) * LS + tau0 + to;
  for (int cr = tid >> 7; cr < 64; cr += 4)
    corr[cbase + (size_t)cr * LS] = wt[to * 65 + cr];
}

// ---------------------------------------------------------------------------
// K2 (merged scales): per-(scale,b) stats, cm partials, peak detect +
// compaction (one global atomic per block) + level-0 histogram.
// Grid: (C_/GCH, B, 3).
// ---------------------------------------------------------------------------
__launch_bounds__(256, 4)
__global__ void k_stats(const float* __restrict__ corrbase, float* __restrict__ cm,
                        double* s1, double* s2, u32* peak_cnt, u32* histA,
                        u32* pkbase) {
  __shared__ __align__(16) float rows[GCH * 1024];
  __shared__ u32 hist_s[256];
  __shared__ double red_d[8];
  __shared__ u32 wv[4], wbase[4];
  const int tid = threadIdx.x;
  const int sidx = blockIdx.z;
  const int b = blockIdx.y;
  const int sb = sidx * 16 + b;
  const int Ls = 1024 >> sidx;
  const int c0 = blockIdx.x * GCH;
  const int lane = tid & 63;
  const int wave = tid >> 6;
  hist_s[tid] = 0;
  {
    const float4* src4 =
        (const float4*)(corrbase + co(sidx) + ((size_t)b * C_ + c0) * Ls);
    float4* dst4 = (float4*)rows;
    const int n4 = GCH * Ls / 4;
    for (int i = tid; i < n4; i += 256) dst4[i] = src4[i];
  }
  __syncthreads();
  const int nt = Ls >> 8;         // taus per thread: 4/2/1
  float cmacc[4] = {0.f, 0.f, 0.f, 0.f};
  double ls1 = 0.0, ls2 = 0.0;
  u32 mycnt = 0;
  // ---- phase 1: stats + peak count + level-0 hist
  for (int g = 0; g < GCH; ++g) {
    const float* row = rows + g * Ls;
    for (int i = 0; i < nt; ++i) {
      int t = tid + (i << 8);
      float v = row[t];
      cmacc[i] += v;
      ls1 += (double)v;
      ls2 += (double)v * (double)v;
      bool pk = (t >= 1) && (t <= Ls - 2) && (v > row[t - 1]) && (v > row[t + 1]);
      if (pk) {
        ++mycnt;
        atomicAdd(&hist_s[f2key(v) >> 24], 1u);
      }
    }
  }
  // block-scan peak counts -> single global atomic for base
  u32 wc = mycnt;
  for (int off = 32; off; off >>= 1) wc += __shfl_down(wc, off, 64);
  if (lane == 0) wv[wave] = wc;
  __syncthreads();
  if (tid == 0) {
    u32 t = 0;
    for (int w = 0; w < 4; ++w) { wbase[w] = t; t += wv[w]; }
    u32 base = atomicAdd(&peak_cnt[sb * 16], t);
    for (int w = 0; w < 4; ++w) wbase[w] += base;
  }
  __syncthreads();
  // ---- phase 2: re-detect, compacted write at deterministic offsets
  const u32 cap = pk_cap(sidx);
  u32* dst_pk = pkbase + pk_off(sidx) + (u32)b * cap;
  u32 off_w = wbase[wave];
  const u64 below = (1ull << lane) - 1ull;
  for (int g = 0; g < GCH; ++g) {
    const float* row = rows + g * Ls;
    for (int i = 0; i < nt; ++i) {
      int t = tid + (i << 8);
      float v = row[t];
      bool pk = (t >= 1) && (t <= Ls - 2) && (v > row[t - 1]) && (v > row[t + 1]);
      u64 mask = __ballot(pk);
      if (pk) {
        u32 idx = off_w + (u32)__popcll(mask & below);
        if (idx < cap) dst_pk[idx] = f2key(v);
      }
      off_w += (u32)__popcll(mask);
    }
  }
  // cm partials: one unsafe float atomic per owned tau
  for (int i = 0; i < nt; ++i) {
    int t = tid + (i << 8);
    unsafeAtomicAdd(&cm[sb * 1024 + t], cmacc[i]);
  }
  // s1/s2: wave reduce -> block reduce -> one double atomic per block
  for (int off = 32; off; off >>= 1) {
    ls1 += __shfl_down(ls1, off, 64);
    ls2 += __shfl_down(ls2, off, 64);
  }
  if (lane == 0) { red_d[wave] = ls1; red_d[4 + wave] = ls2; }
  __syncthreads();
  if (tid == 0) {
    unsafeAtomicAdd(&s1[sb], red_d[0] + red_d[1] + red_d[2] + red_d[3]);
    unsafeAtomicAdd(&s2[sb], red_d[4] + red_d[5] + red_d[6] + red_d[7]);
  }
  if (hist_s[tid]) atomicAdd(&histA[sb * 256 + tid], hist_s[tid]);
}

// ---------------------------------------------------------------------------
// K3 (merged): one block per (scale,b). cm pk-count, MLP -> kvals, level-0
// radix scan (snapshot-then-write). Energy computed redundantly per block.
// ---------------------------------------------------------------------------
__global__ void k_mlp(const float* __restrict__ cm, const double* s1,
                      const double* s2, const u32* peak_cnt, const u32* histA,
                      int* rank_s, u32* prefix_s, u32* active, float* thresh,
                      const float* w1, const float* b1, const float* w2,
                      const float* b2, const float* w3, const float* b3) {
  __shared__ float wls[673];       // w1(96) b1(32) w2(512) b2(16) w3(16) b3(1)
  __shared__ float cmrow[1024];
  __shared__ int red_i[4];
  __shared__ u32 cum[256];
  const int tid = threadIdx.x;
  const int sb = blockIdx.x;
  const int sidx = sb >> 4;
  const int Ls = 1024 >> sidx;
  for (int i = tid; i < 96; i += 256) wls[i] = w1[i];
  for (int i = tid; i < 32; i += 256) wls[96 + i] = b1[i];
  for (int i = tid; i < 512; i += 256) wls[128 + i] = w2[i];
  if (tid < 16) wls[640 + tid] = b2[tid];
  if (tid < 16) wls[656 + tid] = w3[tid];
  if (tid == 0) wls[672] = b3[0];
  for (int i = tid; i < Ls; i += 256) cmrow[i] = cm[sb * 1024 + i];
  __syncthreads();
  int cnt = 0;
  for (int t = 1 + tid; t <= Ls - 2; t += 256) {
    float v = cmrow[t];
    cnt += (v > cmrow[t - 1]) && (v > cmrow[t + 1]);
  }
  for (int off = 32; off; off >>= 1) cnt += __shfl_down(cnt, off, 64);
  if ((tid & 63) == 0) red_i[tid >> 6] = cnt;
  __syncthreads();
  if (tid == 0) {
    double tot = 0.0;
    for (int j = 0; j < 16; ++j) tot += s2[sidx * 16 + j];
    float f0 = (float)(tot / (16.0 * (double)Ls));
    double N = (double)C_ * (double)Ls;
    float f1 = (float)((s2[sb] - s1[sb] * s1[sb] / N) / (N - 1.0));
    float f2 = (float)(red_i[0] + red_i[1] + red_i[2] + red_i[3]);
    float h1[32];
    for (int j = 0; j < 32; ++j)
      h1[j] = fmaxf(0.f, wls[j * 3] * f0 + wls[j * 3 + 1] * f1 + wls[j * 3 + 2] * f2 + wls[96 + j]);
    float h2[16];
    for (int j = 0; j < 16; ++j) {
      float a = wls[640 + j];
      for (int i = 0; i < 32; ++i) a += wls[128 + j * 32 + i] * h1[i];
      h2[j] = fmaxf(0.f, a);
    }
    float z = wls[672];
    for (int i = 0; i < 16; ++i) z += wls[656 + i] * h2[i];
    float ratio = 1.0f / (1.0f + __expf(-z));
    int kv = (int)(ratio * (float)Ls);
    kv = min(max(kv, 1), Ls);
    int cntb = (int)peak_cnt[sb * 16];
    active[sb] = (u32)(cntb > kv);
    thresh[sb] = -INFINITY;
    rank_s[sb] = kv;
    prefix_s[sb] = 0;
  }
  __syncthreads();
  // level-0 radix scan: parallel suffix-scan over 256 bins
  cum[tid] = histA[sb * 256 + tid];
  __syncthreads();
  for (int off = 1; off < 256; off <<= 1) {
    u32 add = (tid + off < 256) ? cum[tid + off] : 0u;
    __syncthreads();
    cum[tid] += add;
    __syncthreads();
  }
  u32 act_b = active[sb];
  u32 r = act_b ? (u32)rank_s[sb] : 0u;
  u32 cc = cum[tid];
  u32 cnext = (tid == 255) ? 0u : cum[tid + 1];
  __syncthreads();          // all snapshots done before any write
  if (act_b && r > 0 && cc >= r && cnext < r) {
    prefix_s[sb] = (u32)tid << 24;
    rank_s[sb] = (int)(r - cnext);
  }
}

// ---------------------------------------------------------------------------
// K_sel (levels 1..3): full key scan, LDS->global hist, ticket finisher does
// the parallel suffix-scan + snapshot-write refine. Grid: 3*16*NB_SEL.
// ---------------------------------------------------------------------------
__global__ void k_sel(const u32* __restrict__ pkbase, const u32* peak_cnt,
                      const u32* active, int* rank_s, u32* prefix_s,
                      u32* hist, u32* done, float* thresh, int level) {
  __shared__ u32 hist_s[256];
  __shared__ u32 cum[256];
  __shared__ u32 islast;
  const int tid = threadIdx.x;
  const int sb = blockIdx.x / NB_SEL;
  const int blk = blockIdx.x % NB_SEL;
  const int sidx = sb >> 4;
  hist_s[tid] = 0;
  if (tid == 0) islast = 0;
  __syncthreads();
  const int act = (int)active[sb];
  const u32 cap = pk_cap(sidx);
  u32 cnt = peak_cnt[sb * 16];
  if (cnt > cap) cnt = cap;
  if (act) {
    const u32 pref = prefix_s[sb];
    const int hi_sh = 32 - 8 * level;
    const int b_sh = 24 - 8 * level;
    const u32 lo = (u32)(((u64)cnt * (u64)blk) / NB_SEL);
    const u32 hi = (u32)(((u64)cnt * (u64)(blk + 1)) / NB_SEL);
    const u32* src = pkbase + pk_off(sidx) + (u32)(sb & 15) * cap;
    for (u32 i = lo + tid; i < hi; i += 256) {
      u32 key = src[i];
      if ((key >> hi_sh) == (pref >> hi_sh))
        atomicAdd(&hist_s[(key >> b_sh) & 255u], 1u);
    }
  }
  __syncthreads();
  if (hist_s[tid]) atomicAdd(&hist[sb * 256 + tid], hist_s[tid]);
  __syncthreads();                        // barrier drains all vmem (vmcnt(0))
  if (tid == 0) {
    __threadfence();
    u32 t = atomicAdd(&done[(level - 1) * 48 + sb], 1u);
    if (t == NB_SEL - 1) islast = 1;
  }
  __syncthreads();
  if (!islast) return;
  // ---- finisher (exactly one block per (scale,b))
  __threadfence();
  u32 hv = atomicAdd(&hist[sb * 256 + tid], 0u);    // atomic read
  cum[tid] = hv;
  hist[sb * 256 + tid] = 0;               // ready for next level
  __syncthreads();
  for (int off = 1; off < 256; off <<= 1) {
    u32 add = (tid + off < 256) ? cum[tid + off] : 0u;
    __syncthreads();
    cum[tid] += add;
    __syncthreads();
  }
  u32 r = act ? (u32)rank_s[sb] : 0u;
  u32 pref2 = act ? prefix_s[sb] : 0u;
  u32 cc = cum[tid];
  u32 cnext = (tid == 255) ? 0u : cum[tid + 1];
  __syncthreads();                        // snapshots before write
  if (act && r > 0 && cc >= r && cnext < r) {
    u32 np = pref2 | ((u32)tid << (24 - 8 * level));
    prefix_s[sb] = np;
    rank_s[sb] = (int)(r - cnext);
    if (level == 3) thresh[sb] = key2f(np);
  }
}

// ---------------------------------------------------------------------------
// K5a (merged): per-(scale,b,c) softmax stats. Grid: (8192, 3).
// ---------------------------------------------------------------------------
__global__ void k_softstats(const float* __restrict__ corrbase, const float* thresh,
                            float2* __restrict__ mZ) {
  __shared__ float row[1024];
  __shared__ float red_s[8];
  const int tid = threadIdx.x;
  const int bc = blockIdx.x;
  const int sidx = blockIdx.y;
  const int Ls = 1024 >> sidx;
  const float th = thresh[sidx * 16 + (bc >> 9)];
  const float* src = corrbase + co(sidx) + (size_t)bc * Ls;
  for (int t = tid; t < Ls; t += 256) row[t] = src[t];
  __syncthreads();
  float mx = 0.f;   // zeros always present in attn row -> true max >= 0
  for (int t = tid; t < Ls; t += 256) {
    float v = row[t];
    bool pk = (t >= 1) && (t <= Ls - 2) && (v > row[t - 1]) && (v > row[t + 1]) && (v >= th);
    if (pk) mx = fmaxf(mx, v);
  }
  for (int off = 32; off; off >>= 1) mx = fmaxf(mx, __shfl_down(mx, off, 64));
  if ((tid & 63) == 0) red_s[tid >> 6] = mx;
  __syncthreads();
  float m = fmaxf(fmaxf(red_s[0], red_s[1]), fmaxf(red_s[2], red_s[3]));
  float zs = 0.f;
  for (int t = tid; t < Ls; t += 256) {
    float v = row[t];
    bool pk = (t >= 1) && (t <= Ls - 2) && (v > row[t - 1]) && (v > row[t + 1]) && (v >= th);
    float a = pk ? v : 0.f;
    zs += __expf(a - m);
  }
  for (int off = 32; off; off >>= 1) zs += __shfl_down(zs, off, 64);
  if ((tid & 63) == 0) red_s[4 + (tid >> 6)] = zs;
  __syncthreads();
  if (tid == 0) {
    float Z = red_s[4] + red_s[5] + red_s[6] + red_s[7];
    mZ[sidx * 8192 + bc] = make_float2(m, 1.0f / Z);
  }
}

// ---------------------------------------------------------------------------
// K5b (s=2 and s=4 in ONE dispatch): o_s[b][tau][c] = softmax-w * pooled v.
// grid (6, 8, 16): x<2 -> s=4 tile x; x>=2 -> s=2 tile x-2. 128-tau tiles.
// ---------------------------------------------------------------------------
__launch_bounds__(256, 4)
__global__ void k_apply2(const float* __restrict__ corr2c, const float* __restrict__ corr4c,
                         const float* __restrict__ V,
                         const float2* __restrict__ mZ2, const float2* __restrict__ mZ4,
                         const float* __restrict__ th2, const float* __restrict__ th4,
                         float* __restrict__ o2p, float* __restrict__ o4p) {
  __shared__ float ct[64][131];      // col j holds t = t0-1+j (clamped)
  __shared__ float m_s[64], rz_s[64];
  const int tid = threadIdx.x;
  const int b = blockIdx.z;
  const int c0 = blockIdx.y << 6;
  const int xb = blockIdx.x;
  const int is4 = (xb < 2);
  const int s = is4 ? 4 : 2;
  const int Ls = is4 ? 256 : 512;
  const int t0 = (is4 ? xb : (xb - 2)) << 7;
  const float* corr = is4 ? corr4c : corr2c;
  const float2* mZ = is4 ? mZ4 : mZ2;
  const float* thp = is4 ? th4 : th2;
  float* o = is4 ? o4p : o2p;
  {
    const int row0 = tid >> 7, jc = tid & 127;
    for (int rr = row0; rr < 64; rr += 2) {
      const float* src = corr + ((size_t)b * C_ + c0 + rr) * Ls;
      for (int j = jc; j < 130; j += 128) {
        int t = t0 - 1 + j;
        t = max(0, min(t, Ls - 1));
        ct[rr][j] = src[t];
      }
    }
  }
  if (tid < 64) {
    float2 v = mZ[b * C_ + c0 + tid];
    m_s[tid] = v.x; rz_s[tid] = v.y;
  }
  __syncthreads();
  const float th = thp[b];
  const int cl = tid & 63, ts = tid >> 6;
  for (int ii = 0; ii < 32; ++ii) {
    int tl = ts + (ii << 2);
    int tg = t0 + tl;
    float vm = ct[cl][tl], vc = ct[cl][tl + 1], vp = ct[cl][tl + 2];
    bool pk = (tg >= 1) && (tg <= Ls - 2) && (vc > vm) && (vc > vp) && (vc >= th);
    float a = pk ? vc : 0.f;
    float w = __expf(a - m_s[cl]) * rz_s[cl];
    size_t vb = ((size_t)b * L_ + (size_t)tg * s) * C_ + c0 + cl;
    float vv;
    if (s == 2) vv = (V[vb] + V[vb + C_]) * 0.5f;
    else vv = ((V[vb] + V[vb + C_]) + (V[vb + 2 * C_] + V[vb + 3 * C_])) * 0.25f;
    o[((size_t)b * Ls + tg) * C_ + c0 + cl] = w * vv;
  }
}

// ---------------------------------------------------------------------------
// K5b-final (s=1): out = sw0*w*v + sw1*lerp(o2) + sw2*lerp(o4). 128-tau tiles.
// ---------------------------------------------------------------------------
__launch_bounds__(256, 4)
__global__ void k_apply_final(const float* __restrict__ corr, const float* __restrict__ V,
                              const float2* __restrict__ mZ, const float* thresh,
                              const float* __restrict__ o2, const float* __restrict__ o4,
                              const float* __restrict__ sw, float* __restrict__ out) {
  __shared__ float ct[64][131];
  __shared__ float m_s[64], rz_s[64];
  const int Ls = 1024;
  const int tid = threadIdx.x;
  const int b = blockIdx.z;
  const int c0 = blockIdx.y << 6;
  const int t0 = blockIdx.x << 7;
  {
    const int row0 = tid >> 7, jc = tid & 127;
    for (int rr = row0; rr < 64; rr += 2) {
      const float* src = corr + ((size_t)b * C_ + c0 + rr) * Ls;
      for (int j = jc; j < 130; j += 128) {
        int t = t0 - 1 + j;
        t = max(0, min(t, Ls - 1));
        ct[rr][j] = src[t];
      }
    }
  }
  if (tid < 64) {
    float2 v = mZ[b * C_ + c0 + tid];
    m_s[tid] = v.x; rz_s[tid] = v.y;
  }
  __syncthreads();
  const float th = thresh[b];
  const float sw0 = sw[0], sw1 = sw[1], sw2 = sw[2];
  const int cl = tid & 63, ts = tid >> 6;
  for (int ii = 0; ii < 32; ++ii) {
    int tl = ts + (ii << 2);
    int tg = t0 + tl;
    float vm = ct[cl][tl], vc = ct[cl][tl + 1], vp = ct[cl][tl + 2];
    bool pk = (tg >= 1) && (tg <= Ls - 2) && (vc > vm) && (vc > vp) && (vc >= th);
    float a = pk ? vc : 0.f;
    float w = __expf(a - m_s[cl]) * rz_s[cl];
    float v1 = V[((size_t)b * L_ + tg) * C_ + c0 + cl];
    float r = sw0 * w * v1;
    {
      float srcp = fmaxf((tg + 0.5f) * 0.5f - 0.5f, 0.f);
      int x0 = (int)srcp;
      float lam = srcp - (float)x0;
      int x1 = min(x0 + 1, 511);
      const float* p = o2 + (size_t)b * 512 * C_ + c0 + cl;
      r += sw1 * ((1.f - lam) * p[(size_t)x0 * C_] + lam * p[(size_t)x1 * C_]);
    }
    {
      float srcp = fmaxf((tg + 0.5f) * 0.25f - 0.5f, 0.f);
      int x0 = (int)srcp;
      float lam = srcp - (float)x0;
      int x1 = min(x0 + 1, 255);
      const float* p = o4 + (size_t)b * 256 * C_ + c0 + cl;
      r += sw2 * ((1.f - lam) * p[(size_t)x0 * C_] + lam * p[(size_t)x1 * C_]);
    }
    out[((size_t)b * L_ + tg) * C_ + c0 + cl] = r;
  }
}

// ---------------------------------------------------------------------------
extern "C" void kernel_launch(void* const* d_in, const int* in_sizes, int n_in,
                              void* d_out, int out_size, void* d_ws, size_t ws_size,
                              hipStream_t stream) {
  const float* Q  = (const float*)d_in[0];
  const float* Kk = (const float*)d_in[1];
  const float* V  = (const float*)d_in[2];
  const float* sw = (const float*)d_in[3];
  const float* w1 = (const float*)d_in[4];
  const float* b1 = (const float*)d_in[5];
  const float* w2 = (const float*)d_in[6];
  const float* b2 = (const float*)d_in[7];
  const float* w3 = (const float*)d_in[8];
  const float* b3 = (const float*)d_in[9];
  float* out = (float*)d_out;

  char* ws = (char*)d_ws;
  size_t p = 0;
  auto alloc = [&](size_t n) { char* r = ws + p; p = (p + n + 255) & ~(size_t)255; return r; };
  // corr for all 3 scales: [s1 | s2 | s4], elem offsets 0 / 8388608 / 12582912
  float*  corr = (float*)alloc((size_t)(8388608 + 4194304 + 2097152) * 4);  // 58.7 MB
  // o-region: o2 (16.8MB) + o4 (8.4MB); pk_buf (22.5MB) aliases it (pk dies
  // after k_sel level 3; o2/o4 born at k_apply, strictly later in-stream).
  char*   oreg = alloc((size_t)25165824);
  float*  o2   = (float*)oreg;
  float*  o4   = (float*)(oreg + 16777216);
  u32*    pk   = (u32*)oreg;
  float*  cm       = (float*)alloc(3 * 16 * 1024 * 4);
  float2* mZ       = (float2*)alloc(3 * 16 * 512 * 8);
  double* s1d      = (double*)alloc(48 * 8);
  double* s2d      = (double*)alloc(48 * 8);
  u32*    histA    = (u32*)alloc(3 * 16 * 256 * 4);
  u32*    histB    = (u32*)alloc(3 * 16 * 256 * 4);
  u32*    peak_cnt = (u32*)alloc(3 * 16 * 16 * 4);   // padded: 1 counter / 64B
  u32*    done     = (u32*)alloc(144 * 4);
  int*    rank_s   = (int*)alloc(48 * 4);
  u32*    prefix_s = (u32*)alloc(48 * 4);
  u32*    active   = (u32*)alloc(48 * 4);
  float*  thresh   = (float*)alloc(48 * 4);

  k_init<<<dim3(16), dim3(256), 0, stream>>>(histA, histB, peak_cnt, done,
                                             s1d, s2d, cm);
  k_corr1<1><<<dim3(128, 8), dim3(512), 0, stream>>>(Q, Kk, corr);
  k_corr1<2><<<dim3(128, 4), dim3(512), 0, stream>>>(Q, Kk, corr + 8388608);
  k_corr1<4><<<dim3(128, 2), dim3(512), 0, stream>>>(Q, Kk, corr + 12582912);
  k_stats<<<dim3(C_ / GCH, B_, 3), dim3(256), 0, stream>>>(
      corr, cm, s1d, s2d, peak_cnt, histA, pk);
  k_mlp<<<dim3(48), dim3(256), 0, stream>>>(
      cm, s1d, s2d, peak_cnt, histA, rank_s, prefix_s, active, thresh,
      w1, b1, w2, b2, w3, b3);
  for (int level = 1; level <= 3; ++level)
    k_sel<<<dim3(48 * NB_SEL), dim3(256), 0, stream>>>(
        pk, peak_cnt, active, rank_s, prefix_s, histB, done, thresh, level);
  k_softstats<<<dim3(8192, 3), dim3(256), 0, stream>>>(corr, thresh, mZ);
  k_apply2<<<dim3(6, 8, 16), dim3(256), 0, stream>>>(
      corr + 8388608, corr + 12582912, V, mZ + 8192, mZ + 2 * 8192,
      thresh + 16, thresh + 32, o2, o4);
  k_apply_final<<<dim3(8, 8, 16), dim3(256), 0, stream>>>(
      corr, V, mZ, thresh, o2, o4, sw, out);
}

// Round 9
// 758.872 us; speedup vs baseline: 1.2228x; 1.0070x over previous
//
#include <hip/hip_runtime.h>
#include <math.h>

typedef unsigned int u32;
typedef unsigned long long u64;
typedef float f4 __attribute__((ext_vector_type(4)));

#define B_ 16
#define L_ 1024
#define H_ 8
#define E_ 64
#define C_ 512            // H_*E_
#define NB_SEL 32         // blocks per (scale,b) in k_sel
#define GCH 8             // channels per k_stats block
#define TC 32             // k_corr time-chunk
#define CAP1 192          // k_corr ring rows (mod-192)
#define KGRP 56           // K groups: 48 ring + 8 dup (rows 0..31 @ 192..223)

// scale indexing: sidx 0 -> s=1 (Ls=1024), 1 -> s=2 (512), 2 -> s=4 (256)
__device__ __forceinline__ size_t co(int sidx) {       // corr elem offset
  return sidx == 0 ? 0u : (sidx == 1 ? 8388608u : 12582912u);
}
__device__ __forceinline__ u32 pk_off(int sidx) {      // pk elem offset in o-region
  return sidx == 0 ? 0u : (sidx == 1 ? 3211264u : 4816896u);
}
__device__ __forceinline__ u32 pk_cap(int sidx) { return 200704u >> sidx; }

__device__ __forceinline__ u32 f2key(float f) {
  u32 u = __float_as_uint(f);
  return (u & 0x80000000u) ? ~u : (u | 0x80000000u);
}
__device__ __forceinline__ float key2f(u32 k) {
  u32 u = (k & 0x80000000u) ? (k ^ 0x80000000u) : ~k;
  return __uint_as_float(u);
}

// ---------------------------------------------------------------------------
// K_init: zero control state once (single-pass pipeline -> no mid-run resets)
// ---------------------------------------------------------------------------
__global__ void k_init(u32* histA, u32* histB, u32* peak_cnt, u32* done,
                       double* s1, double* s2, float* cm) {
  const int gid = blockIdx.x * 256 + threadIdx.x;
  const int gs = gridDim.x * 256;
  for (int i = gid; i < 3 * 16 * 256; i += gs) { histA[i] = 0; histB[i] = 0; }
  for (int i = gid; i < 3 * 16 * 1024; i += gs) cm[i] = 0.f;
  for (int i = gid; i < 3 * 16 * 16; i += gs) peak_cnt[i] = 0;
  for (int i = gid; i < 144; i += gs) done[i] = 0;
  for (int i = gid; i < 48; i += gs) { s1[i] = 0.0; s2[i] = 0.0; }
}

// pooled gather: mean over S raw rows at pooled index tk, column e.
template<int S>
__device__ __forceinline__ float gpool(const float* base, int tk, int e) {
  float v = base[(size_t)(tk * S) * C_ + e];
  if constexpr (S >= 2) v += base[(size_t)(tk * S + 1) * C_ + e];
  if constexpr (S == 4) {
    v += base[(size_t)(tk * S + 2) * C_ + e];
    v += base[(size_t)(tk * S + 3) * C_ + e];
  }
  constexpr float sc = (S == 1) ? 1.f : (S == 2) ? 0.5f : 0.25f;
  if constexpr (S >= 2) v *= sc;
  return v;
}

// ---------------------------------------------------------------------------
// K1 (all scales): circular cross-correlation, fp32 direct, register-tiled.
// r8's verified structure, now parameterized on TAUW (taus per wave):
//  - TAUW=16: 128-tau blocks (bit-identical to r8's proven kernel).
//  - TAUW=8 : 64-tau blocks for S=4 -> grid 512 blocks = 2/CU = 4 waves/SIMD
//    (was 256 blocks = 1/CU = 2 waves/SIMD, latency-exposed).
//  Window invariant: bp = (128-TAUW-slot)+cph; bp+TAUW+30 <= cph+158 for all
//  TAUW -> ring-192 + dup-image + ONE-barrier-per-chunk logic unchanged.
//  4-row-interleaved LDS groups (0 bank conflicts, verified r7); km/q all
//  b128; reg-staged with pooling folded into gathers; VGPR 64 (r8 measured).
// ---------------------------------------------------------------------------
template<int S, int TAUW>
__launch_bounds__(512, 4)
__global__ void k_corr1(const float* __restrict__ Q, const float* __restrict__ K,
                        float* __restrict__ corr) {
  constexpr int LS = 1024 / S;
  constexpr int LMASK = LS - 1;
  constexpr int NCHUNK = LS / TC;
  constexpr int NTAU = 8 * TAUW;      // taus per block
  constexpr int WIN = TAUW + 31;      // km window rows
  constexpr int NG = (WIN + 3) >> 2;  // km groups (12 or 10)
  __shared__ __align__(16) float ksT[KGRP * 256];   // 56KB [p/4][e][4]
  __shared__ __align__(16) float qT[2 * 8 * 256];   // 16KB [buf][t/4][e][4]
  const int tid = threadIdx.x;        // 0..511
  const int e = tid & 63;
  const int w = tid >> 6;             // wave 0..7
  const int slot = __builtin_amdgcn_readfirstlane(w * TAUW);
  const int bh = blockIdx.x;
  const int tau0 = blockIdx.y * NTAU;
  const int b = bh >> 3, h = bh & 7;
  const size_t gbase = (size_t)b * L_ * C_ + (size_t)h * 64;
  const float* Qb = Q + gbase;
  const float* Kb = K + gbase;
  const int e4 = e << 2;                    // lane's float offset inside group
  const int bp0 = 128 - TAUW - slot;        // wave-uniform

  float acc[TAUW];
#pragma unroll
  for (int i = 0; i < TAUW; ++i) acc[i] = 0.f;

  // prologue: K logical rows 0..159 (5 passes; wave w stages rows pass*32+4w..+3);
  // q rows 0..31 into buf0 (wave w -> group w). All pooled gathers.
#pragma unroll
  for (int pass = 0; pass < 5; ++pass) {
    const int p0 = pass * 32 + (w << 2);
    f4 v;
#pragma unroll
    for (int j = 0; j < 4; ++j) {
      int tk = (p0 + j - tau0 - 127 + 2048) & LMASK;
      v[j] = gpool<S>(Kb, tk, e);
    }
    *(f4*)&ksT[(p0 >> 2) * 256 + e4] = v;
    if (p0 < 32) *(f4*)&ksT[((p0 + 192) >> 2) * 256 + e4] = v;  // dup image
  }
  {
    f4 v;
#pragma unroll
    for (int j = 0; j < 4; ++j)
      v[j] = gpool<S>(Qb, (w << 2) + j, e);
    *(f4*)&qT[w * 256 + e4] = v;
  }
  __syncthreads();

  int cph = 0;                              // (chunk*32) mod 192
  for (int chunk = 0; chunk < NCHUNK; ++chunk) {
    const int t0 = chunk * TC;
    const bool more = (chunk + 1 < NCHUNK);
    // ---- issue global loads for chunk+1 (latency hides under compute) ----
    f4 kr, qr;
    int sr = 0;
    if (more) {
      int sp = cph + 160; if (sp >= CAP1) sp -= CAP1;  // 32-aligned
      sr = sp + (w << 2);                              // <= 188, no wrap
#pragma unroll
      for (int j = 0; j < 4; ++j) {
        int l = t0 + 160 + (w << 2) + j;
        int tk = (l - tau0 - 127 + 2048) & LMASK;
        kr[j] = gpool<S>(Kb, tk, e);
      }
#pragma unroll
      for (int j = 0; j < 4; ++j)
        qr[j] = gpool<S>(Qb, (t0 + TC + (w << 2) + j) & LMASK, e);
    }
    // ---- compute: TAUW taus x 32 jt over a WIN-row k-window, all b128 ----
    int bp = bp0 + cph; if (bp >= CAP1) bp -= CAP1;    // wave-uniform
    const int g0 = bp >> 2;                            // group base
    f4 km4[NG];                                        // rows bp..bp+WIN-1
#pragma unroll
    for (int j = 0; j < NG; ++j)
      km4[j] = *(const f4*)&ksT[(g0 + j) * 256 + e4];  // dup covers >= group 48
    const float* qb = qT + (chunk & 1) * 2048;
#pragma unroll
    for (int g = 0; g < 8; ++g) {
      f4 qv = *(const f4*)&qb[g * 256 + e4];
#pragma unroll
      for (int k = 0; k < 4; ++k) {
        const int jt = (g << 2) + k;
#pragma unroll
        for (int i = 0; i < TAUW; ++i) {
          const int m = TAUW - 1 + jt - i;             // 0..WIN-1, compile-time
          acc[i] = fmaf(qv[k], km4[m >> 2][m & 3], acc[i]);
        }
      }
    }
    // ---- write staged data (logical rows disjoint from read window) ------
    if (more) {
      *(f4*)&ksT[(sr >> 2) * 256 + e4] = kr;
      if (sr < 32) *(f4*)&ksT[((sr + 192) >> 2) * 256 + e4] = kr;
      float* qn = qT + (((chunk & 1) ^ 1)) * 2048;
      *(f4*)&qn[w * 256 + e4] = qr;
    }
    __syncthreads();    // staged writes visible before next chunk's reads
    cph += 32; if (cph >= CAP1) cph -= CAP1;
  }
  // transpose in LDS, coalesced write (tau-contiguous rows) ----------------
  float* wt = ksT;  // NTAU*65 <= 8320 floats <= 14336
#pragma unroll
  for (int i = 0; i < TAUW; ++i) wt[(slot + i) * 65 + e] = acc[i];
  __syncthreads();
  const int to = tid & (NTAU - 1);
  const size_t cbase = ((size_t)b * C_ + (size_t)h * 64) * LS + tau0 + to;
  for (int cr = tid / NTAU; cr < 64; cr += 512 / NTAU)
    corr[cbase + (size_t)cr * LS] = wt[to * 65 + cr];
}

// ---------------------------------------------------------------------------
// K2 (merged scales): per-(scale,b) stats, cm partials, peak detect +
// compaction (one global atomic per block) + level-0 histogram.
// Grid: (C_/GCH, B, 3).
// ---------------------------------------------------------------------------
__launch_bounds__(256, 4)
__global__ void k_stats(const float* __restrict__ corrbase, float* __restrict__ cm,
                        double* s1, double* s2, u32* peak_cnt, u32* histA,
                        u32* pkbase) {
  __shared__ __align__(16) float rows[GCH * 1024];
  __shared__ u32 hist_s[256];
  __shared__ double red_d[8];
  __shared__ u32 wv[4], wbase[4];
  const int tid = threadIdx.x;
  const int sidx = blockIdx.z;
  const int b = blockIdx.y;
  const int sb = sidx * 16 + b;
  const int Ls = 1024 >> sidx;
  const int c0 = blockIdx.x * GCH;
  const int lane = tid & 63;
  const int wave = tid >> 6;
  hist_s[tid] = 0;
  {
    const float4* src4 =
        (const float4*)(corrbase + co(sidx) + ((size_t)b * C_ + c0) * Ls);
    float4* dst4 = (float4*)rows;
    const int n4 = GCH * Ls / 4;
    for (int i = tid; i < n4; i += 256) dst4[i] = src4[i];
  }
  __syncthreads();
  const int nt = Ls >> 8;         // taus per thread: 4/2/1
  float cmacc[4] = {0.f, 0.f, 0.f, 0.f};
  double ls1 = 0.0, ls2 = 0.0;
  u32 mycnt = 0;
  // ---- phase 1: stats + peak count + level-0 hist
  for (int g = 0; g < GCH; ++g) {
    const float* row = rows + g * Ls;
    for (int i = 0; i < nt; ++i) {
      int t = tid + (i << 8);
      float v = row[t];
      cmacc[i] += v;
      ls1 += (double)v;
      ls2 += (double)v * (double)v;
      bool pk = (t >= 1) && (t <= Ls - 2) && (v > row[t - 1]) && (v > row[t + 1]);
      if (pk) {
        ++mycnt;
        atomicAdd(&hist_s[f2key(v) >> 24], 1u);
      }
    }
  }
  // block-scan peak counts -> single global atomic for base
  u32 wc = mycnt;
  for (int off = 32; off; off >>= 1) wc += __shfl_down(wc, off, 64);
  if (lane == 0) wv[wave] = wc;
  __syncthreads();
  if (tid == 0) {
    u32 t = 0;
    for (int w = 0; w < 4; ++w) { wbase[w] = t; t += wv[w]; }
    u32 base = atomicAdd(&peak_cnt[sb * 16], t);
    for (int w = 0; w < 4; ++w) wbase[w] += base;
  }
  __syncthreads();
  // ---- phase 2: re-detect, compacted write at deterministic offsets
  const u32 cap = pk_cap(sidx);
  u32* dst_pk = pkbase + pk_off(sidx) + (u32)b * cap;
  u32 off_w = wbase[wave];
  const u64 below = (1ull << lane) - 1ull;
  for (int g = 0; g < GCH; ++g) {
    const float* row = rows + g * Ls;
    for (int i = 0; i < nt; ++i) {
      int t = tid + (i << 8);
      float v = row[t];
      bool pk = (t >= 1) && (t <= Ls - 2) && (v > row[t - 1]) && (v > row[t + 1]);
      u64 mask = __ballot(pk);
      if (pk) {
        u32 idx = off_w + (u32)__popcll(mask & below);
        if (idx < cap) dst_pk[idx] = f2key(v);
      }
      off_w += (u32)__popcll(mask);
    }
  }
  // cm partials: one unsafe float atomic per owned tau
  for (int i = 0; i < nt; ++i) {
    int t = tid + (i << 8);
    unsafeAtomicAdd(&cm[sb * 1024 + t], cmacc[i]);
  }
  // s1/s2: wave reduce -> block reduce -> one double atomic per block
  for (int off = 32; off; off >>= 1) {
    ls1 += __shfl_down(ls1, off, 64);
    ls2 += __shfl_down(ls2, off, 64);
  }
  if (lane == 0) { red_d[wave] = ls1; red_d[4 + wave] = ls2; }
  __syncthreads();
  if (tid == 0) {
    unsafeAtomicAdd(&s1[sb], red_d[0] + red_d[1] + red_d[2] + red_d[3]);
    unsafeAtomicAdd(&s2[sb], red_d[4] + red_d[5] + red_d[6] + red_d[7]);
  }
  if (hist_s[tid]) atomicAdd(&histA[sb * 256 + tid], hist_s[tid]);
}

// ---------------------------------------------------------------------------
// K3 (merged): one block per (scale,b). cm pk-count, MLP -> kvals, level-0
// radix scan (snapshot-then-write). Energy computed redundantly per block.
// ---------------------------------------------------------------------------
__global__ void k_mlp(const float* __restrict__ cm, const double* s1,
                      const double* s2, const u32* peak_cnt, const u32* histA,
                      int* rank_s, u32* prefix_s, u32* active, float* thresh,
                      const float* w1, const float* b1, const float* w2,
                      const float* b2, const float* w3, const float* b3) {
  __shared__ float wls[673];       // w1(96) b1(32) w2(512) b2(16) w3(16) b3(1)
  __shared__ float cmrow[1024];
  __shared__ int red_i[4];
  __shared__ u32 cum[256];
  const int tid = threadIdx.x;
  const int sb = blockIdx.x;
  const int sidx = sb >> 4;
  const int Ls = 1024 >> sidx;
  for (int i = tid; i < 96; i += 256) wls[i] = w1[i];
  for (int i = tid; i < 32; i += 256) wls[96 + i] = b1[i];
  for (int i = tid; i < 512; i += 256) wls[128 + i] = w2[i];
  if (tid < 16) wls[640 + tid] = b2[tid];
  if (tid < 16) wls[656 + tid] = w3[tid];
  if (tid == 0) wls[672] = b3[0];
  for (int i = tid; i < Ls; i += 256) cmrow[i] = cm[sb * 1024 + i];
  __syncthreads();
  int cnt = 0;
  for (int t = 1 + tid; t <= Ls - 2; t += 256) {
    float v = cmrow[t];
    cnt += (v > cmrow[t - 1]) && (v > cmrow[t + 1]);
  }
  for (int off = 32; off; off >>= 1) cnt += __shfl_down(cnt, off, 64);
  if ((tid & 63) == 0) red_i[tid >> 6] = cnt;
  __syncthreads();
  if (tid == 0) {
    double tot = 0.0;
    for (int j = 0; j < 16; ++j) tot += s2[sidx * 16 + j];
    float f0 = (float)(tot / (16.0 * (double)Ls));
    double N = (double)C_ * (double)Ls;
    float f1 = (float)((s2[sb] - s1[sb] * s1[sb] / N) / (N - 1.0));
    float f2 = (float)(red_i[0] + red_i[1] + red_i[2] + red_i[3]);
    float h1[32];
    for (int j = 0; j < 32; ++j)
      h1[j] = fmaxf(0.f, wls[j * 3] * f0 + wls[j * 3 + 1] * f1 + wls[j * 3 + 2] * f2 + wls[96 + j]);
    float h2[16];
    for (int j = 0; j < 16; ++j) {
      float a = wls[640 + j];
      for (int i = 0; i < 32; ++i) a += wls[128 + j * 32 + i] * h1[i];
      h2[j] = fmaxf(0.f, a);
    }
    float z = wls[672];
    for (int i = 0; i < 16; ++i) z += wls[656 + i] * h2[i];
    float ratio = 1.0f / (1.0f + __expf(-z));
    int kv = (int)(ratio * (float)Ls);
    kv = min(max(kv, 1), Ls);
    int cntb = (int)peak_cnt[sb * 16];
    active[sb] = (u32)(cntb > kv);
    thresh[sb] = -INFINITY;
    rank_s[sb] = kv;
    prefix_s[sb] = 0;
  }
  __syncthreads();
  // level-0 radix scan: parallel suffix-scan over 256 bins
  cum[tid] = histA[sb * 256 + tid];
  __syncthreads();
  for (int off = 1; off < 256; off <<= 1) {
    u32 add = (tid + off < 256) ? cum[tid + off] : 0u;
    __syncthreads();
    cum[tid] += add;
    __syncthreads();
  }
  u32 act_b = active[sb];
  u32 r = act_b ? (u32)rank_s[sb] : 0u;
  u32 cc = cum[tid];
  u32 cnext = (tid == 255) ? 0u : cum[tid + 1];
  __syncthreads();          // all snapshots done before any write
  if (act_b && r > 0 && cc >= r && cnext < r) {
    prefix_s[sb] = (u32)tid << 24;
    rank_s[sb] = (int)(r - cnext);
  }
}

// ---------------------------------------------------------------------------
// K_sel (levels 1..3): full key scan, LDS->global hist, ticket finisher does
// the parallel suffix-scan + snapshot-write refine. Grid: 3*16*NB_SEL.
// ---------------------------------------------------------------------------
__global__ void k_sel(const u32* __restrict__ pkbase, const u32* peak_cnt,
                      const u32* active, int* rank_s, u32* prefix_s,
                      u32* hist, u32* done, float* thresh, int level) {
  __shared__ u32 hist_s[256];
  __shared__ u32 cum[256];
  __shared__ u32 islast;
  const int tid = threadIdx.x;
  const int sb = blockIdx.x / NB_SEL;
  const int blk = blockIdx.x % NB_SEL;
  const int sidx = sb >> 4;
  hist_s[tid] = 0;
  if (tid == 0) islast = 0;
  __syncthreads();
  const int act = (int)active[sb];
  const u32 cap = pk_cap(sidx);
  u32 cnt = peak_cnt[sb * 16];
  if (cnt > cap) cnt = cap;
  if (act) {
    const u32 pref = prefix_s[sb];
    const int hi_sh = 32 - 8 * level;
    const int b_sh = 24 - 8 * level;
    const u32 lo = (u32)(((u64)cnt * (u64)blk) / NB_SEL);
    const u32 hi = (u32)(((u64)cnt * (u64)(blk + 1)) / NB_SEL);
    const u32* src = pkbase + pk_off(sidx) + (u32)(sb & 15) * cap;
    for (u32 i = lo + tid; i < hi; i += 256) {
      u32 key = src[i];
      if ((key >> hi_sh) == (pref >> hi_sh))
        atomicAdd(&hist_s[(key >> b_sh) & 255u], 1u);
    }
  }
  __syncthreads();
  if (hist_s[tid]) atomicAdd(&hist[sb * 256 + tid], hist_s[tid]);
  __syncthreads();                        // barrier drains all vmem (vmcnt(0))
  if (tid == 0) {
    __threadfence();
    u32 t = atomicAdd(&done[(level - 1) * 48 + sb], 1u);
    if (t == NB_SEL - 1) islast = 1;
  }
  __syncthreads();
  if (!islast) return;
  // ---- finisher (exactly one block per (scale,b))
  __threadfence();
  u32 hv = atomicAdd(&hist[sb * 256 + tid], 0u);    // atomic read
  cum[tid] = hv;
  hist[sb * 256 + tid] = 0;               // ready for next level
  __syncthreads();
  for (int off = 1; off < 256; off <<= 1) {
    u32 add = (tid + off < 256) ? cum[tid + off] : 0u;
    __syncthreads();
    cum[tid] += add;
    __syncthreads();
  }
  u32 r = act ? (u32)rank_s[sb] : 0u;
  u32 pref2 = act ? prefix_s[sb] : 0u;
  u32 cc = cum[tid];
  u32 cnext = (tid == 255) ? 0u : cum[tid + 1];
  __syncthreads();                        // snapshots before write
  if (act && r > 0 && cc >= r && cnext < r) {
    u32 np = pref2 | ((u32)tid << (24 - 8 * level));
    prefix_s[sb] = np;
    rank_s[sb] = (int)(r - cnext);
    if (level == 3) thresh[sb] = key2f(np);
  }
}

// ---------------------------------------------------------------------------
// K5a (merged): per-(scale,b,c) softmax stats AND in-place weight write.
// After computing (m, Z) the row (already in LDS) is overwritten with
// w = expf(a - m) / Z -> downstream apply kernels become pure streaming
// (no halo, no peak re-detect, no expf, no mZ buffer). Grid: (8192, 3).
// Safe: each block owns its row exclusively; k_stats read corr earlier.
// ---------------------------------------------------------------------------
__global__ void k_softstats(float* __restrict__ corrbase, const float* thresh) {
  __shared__ float row[1024];
  __shared__ float red_s[8];
  const int tid = threadIdx.x;
  const int bc = blockIdx.x;
  const int sidx = blockIdx.y;
  const int Ls = 1024 >> sidx;
  const float th = thresh[sidx * 16 + (bc >> 9)];
  float* src = corrbase + co(sidx) + (size_t)bc * Ls;
  for (int t = tid; t < Ls; t += 256) row[t] = src[t];
  __syncthreads();
  float mx = 0.f;   // zeros always present in attn row -> true max >= 0
  for (int t = tid; t < Ls; t += 256) {
    float v = row[t];
    bool pk = (t >= 1) && (t <= Ls - 2) && (v > row[t - 1]) && (v > row[t + 1]) && (v >= th);
    if (pk) mx = fmaxf(mx, v);
  }
  for (int off = 32; off; off >>= 1) mx = fmaxf(mx, __shfl_down(mx, off, 64));
  if ((tid & 63) == 0) red_s[tid >> 6] = mx;
  __syncthreads();
  float m = fmaxf(fmaxf(red_s[0], red_s[1]), fmaxf(red_s[2], red_s[3]));
  float zs = 0.f;
  for (int t = tid; t < Ls; t += 256) {
    float v = row[t];
    bool pk = (t >= 1) && (t <= Ls - 2) && (v > row[t - 1]) && (v > row[t + 1]) && (v >= th);
    float a = pk ? v : 0.f;
    zs += __expf(a - m);
  }
  for (int off = 32; off; off >>= 1) zs += __shfl_down(zs, off, 64);
  if ((tid & 63) == 0) red_s[4 + (tid >> 6)] = zs;
  __syncthreads();
  const float Z = red_s[4] + red_s[5] + red_s[6] + red_s[7];
  const float rz = 1.0f / Z;
  // ---- pass 3: in-place weight write (row still valid in LDS) ----
  for (int t = tid; t < Ls; t += 256) {
    float v = row[t];
    bool pk = (t >= 1) && (t <= Ls - 2) && (v > row[t - 1]) && (v > row[t + 1]) && (v >= th);
    float a = pk ? v : 0.f;
    src[t] = __expf(a - m) * rz;
  }
}

// ---------------------------------------------------------------------------
// K5b (s=2 and s=4 in ONE dispatch): o_s[b][tau][c] = w * pooled v.
// w precomputed in-place by k_softstats -> pure streaming transpose+scale.
// grid (6, 8, 16): x<2 -> s=4 tile x; x>=2 -> s=2 tile x-2. 128-tau tiles.
// ---------------------------------------------------------------------------
__launch_bounds__(256, 4)
__global__ void k_apply2(const float* __restrict__ w2c, const float* __restrict__ w4c,
                         const float* __restrict__ V,
                         float* __restrict__ o2p, float* __restrict__ o4p) {
  __shared__ float ct[64][129];
  const int tid = threadIdx.x;
  const int b = blockIdx.z;
  const int c0 = blockIdx.y << 6;
  const int xb = blockIdx.x;
  const int is4 = (xb < 2);
  const int s = is4 ? 4 : 2;
  const int Ls = is4 ? 256 : 512;
  const int t0 = (is4 ? xb : (xb - 2)) << 7;
  const float* wsrc = is4 ? w4c : w2c;
  float* o = is4 ? o4p : o2p;
  {
    const int row0 = tid >> 7, jc = tid & 127;
    for (int rr = row0; rr < 64; rr += 2)
      ct[rr][jc] = wsrc[((size_t)b * C_ + c0 + rr) * Ls + t0 + jc];
  }
  __syncthreads();
  const int cl = tid & 63, ts = tid >> 6;
  for (int ii = 0; ii < 32; ++ii) {
    int tl = ts + (ii << 2);
    int tg = t0 + tl;
    float w = ct[cl][tl];
    size_t vb = ((size_t)b * L_ + (size_t)tg * s) * C_ + c0 + cl;
    float vv;
    if (s == 2) vv = (V[vb] + V[vb + C_]) * 0.5f;
    else vv = ((V[vb] + V[vb + C_]) + (V[vb + 2 * C_] + V[vb + 3 * C_])) * 0.25f;
    o[((size_t)b * Ls + tg) * C_ + c0 + cl] = w * vv;
  }
}

// ---------------------------------------------------------------------------
// K5b-final (s=1): out = sw0*w*v + sw1*lerp(o2) + sw2*lerp(o4). 128-tau tiles.
// w precomputed in-place -> no halo/peak/expf.
// ---------------------------------------------------------------------------
__launch_bounds__(256, 4)
__global__ void k_apply_final(const float* __restrict__ wsrcb, const float* __restrict__ V,
                              const float* __restrict__ o2, const float* __restrict__ o4,
                              const float* __restrict__ sw, float* __restrict__ out) {
  __shared__ float ct[64][129];
  const int Ls = 1024;
  const int tid = threadIdx.x;
  const int b = blockIdx.z;
  const int c0 = blockIdx.y << 6;
  const int t0 = blockIdx.x << 7;
  {
    const int row0 = tid >> 7, jc = tid & 127;
    for (int rr = row0; rr < 64; rr += 2)
      ct[rr][jc] = wsrcb[((size_t)b * C_ + c0 + rr) * Ls + t0 + jc];
  }
  __syncthreads();
  const float sw0 = sw[0], sw1 = sw[1], sw2 = sw[2];
  const int cl = tid & 63, ts = tid >> 6;
  for (int ii = 0; ii < 32; ++ii) {
    int tl = ts + (ii << 2);
    int tg = t0 + tl;
    float w = ct[cl][tl];
    float v1 = V[((size_t)b * L_ + tg) * C_ + c0 + cl];
    float r = sw0 * w * v1;
    {
      float srcp = fmaxf((tg + 0.5f) * 0.5f - 0.5f, 0.f);
      int x0 = (int)srcp;
      float lam = srcp - (float)x0;
      int x1 = min(x0 + 1, 511);
      const float* p = o2 + (size_t)b * 512 * C_ + c0 + cl;
      r += sw1 * ((1.f - lam) * p[(size_t)x0 * C_] + lam * p[(size_t)x1 * C_]);
    }
    {
      float srcp = fmaxf((tg + 0.5f) * 0.25f - 0.5f, 0.f);
      int x0 = (int)srcp;
      float lam = srcp - (float)x0;
      int x1 = min(x0 + 1, 255);
      const float* p = o4 + (size_t)b * 256 * C_ + c0 + cl;
      r += sw2 * ((1.f - lam) * p[(size_t)x0 * C_] + lam * p[(size_t)x1 * C_]);
    }
    out[((size_t)b * L_ + tg) * C_ + c0 + cl] = r;
  }
}

// ---------------------------------------------------------------------------
extern "C" void kernel_launch(void* const* d_in, const int* in_sizes, int n_in,
                              void* d_out, int out_size, void* d_ws, size_t ws_size,
                              hipStream_t stream) {
  const float* Q  = (const float*)d_in[0];
  const float* Kk = (const float*)d_in[1];
  const float* V  = (const float*)d_in[2];
  const float* sw = (const float*)d_in[3];
  const float* w1 = (const float*)d_in[4];
  const float* b1 = (const float*)d_in[5];
  const float* w2 = (const float*)d_in[6];
  const float* b2 = (const float*)d_in[7];
  const float* w3 = (const float*)d_in[8];
  const float* b3 = (const float*)d_in[9];
  float* out = (float*)d_out;

  char* ws = (char*)d_ws;
  size_t p = 0;
  auto alloc = [&](size_t n) { char* r = ws + p; p = (p + n + 255) & ~(size_t)255; return r; };
  // corr for all 3 scales: [s1 | s2 | s4], elem offsets 0 / 8388608 / 12582912
  float*  corr = (float*)alloc((size_t)(8388608 + 4194304 + 2097152) * 4);  // 58.7 MB
  // o-region: o2 (16.8MB) + o4 (8.4MB); pk_buf (22.5MB) aliases it (pk dies
  // after k_sel level 3; o2/o4 born at k_apply, strictly later in-stream).
  char*   oreg = alloc((size_t)25165824);
  float*  o2   = (float*)oreg;
  float*  o4   = (float*)(oreg + 16777216);
  u32*    pk   = (u32*)oreg;
  float*  cm       = (float*)alloc(3 * 16 * 1024 * 4);
  double* s1d      = (double*)alloc(48 * 8);
  double* s2d      = (double*)alloc(48 * 8);
  u32*    histA    = (u32*)alloc(3 * 16 * 256 * 4);
  u32*    histB    = (u32*)alloc(3 * 16 * 256 * 4);
  u32*    peak_cnt = (u32*)alloc(3 * 16 * 16 * 4);   // padded: 1 counter / 64B
  u32*    done     = (u32*)alloc(144 * 4);
  int*    rank_s   = (int*)alloc(48 * 4);
  u32*    prefix_s = (u32*)alloc(48 * 4);
  u32*    active   = (u32*)alloc(48 * 4);
  float*  thresh   = (float*)alloc(48 * 4);

  k_init<<<dim3(16), dim3(256), 0, stream>>>(histA, histB, peak_cnt, done,
                                             s1d, s2d, cm);
  k_corr1<1, 16><<<dim3(128, 8), dim3(512), 0, stream>>>(Q, Kk, corr);
  k_corr1<2, 16><<<dim3(128, 4), dim3(512), 0, stream>>>(Q, Kk, corr + 8388608);
  k_corr1<4, 8><<<dim3(128, 4), dim3(512), 0, stream>>>(Q, Kk, corr + 12582912);
  k_stats<<<dim3(C_ / GCH, B_, 3), dim3(256), 0, stream>>>(
      corr, cm, s1d, s2d, peak_cnt, histA, pk);
  k_mlp<<<dim3(48), dim3(256), 0, stream>>>(
      cm, s1d, s2d, peak_cnt, histA, rank_s, prefix_s, active, thresh,
      w1, b1, w2, b2, w3, b3);
  for (int level = 1; level <= 3; ++level)
    k_sel<<<dim3(48 * NB_SEL), dim3(256), 0, stream>>>(
        pk, peak_cnt, active, rank_s, prefix_s, histB, done, thresh, level);
  k_softstats<<<dim3(8192, 3), dim3(256), 0, stream>>>(corr, thresh);
  k_apply2<<<dim3(6, 8, 16), dim3(256), 0, stream>>>(
      corr + 8388608, corr + 12582912, V, o2, o4);
  k_apply_final<<<dim3(8, 8, 16), dim3(256), 0, stream>>>(
      corr, V, o2, o4, sw, out);
}